// Round 3
// baseline (1018.506 us; speedup 1.0000x reference)
//
#include <hip/hip_runtime.h>
#include <math.h>

typedef unsigned short u16;
typedef __attribute__((ext_vector_type(8))) short short8;
typedef __attribute__((ext_vector_type(4))) float f32x4;

#define DIMC   768
#define TOK    4096
#define NQKVC  2304
#define FFC    3072
#define NEXP   8
#define NHEAD  12
#define HDIM   64
#define SEQ    1024
#define NBATCH 4
#define SLOTS  9216   // 8192 + per-expert 128-pad slack (max 9208)

// ---------- bf16 helpers ----------
__device__ __forceinline__ float bf2f(u16 v) {
    unsigned int u = ((unsigned int)v) << 16;
    float f; __builtin_memcpy(&f, &u, 4); return f;
}
__device__ __forceinline__ u16 f2bf(float f) {
    unsigned int u; __builtin_memcpy(&u, &f, 4);
    u = (u + 0x7fffu + ((u >> 16) & 1u)) >> 16;
    return (u16)u;
}

// async global->LDS, 16B per lane. lds base must be wave-uniform; HW adds lane*16.
__device__ __forceinline__ void async16(u16* lds, const u16* gp) {
    __builtin_amdgcn_global_load_lds(
        (const __attribute__((address_space(1))) unsigned int*)gp,
        (__attribute__((address_space(3))) unsigned int*)lds, 16, 0, 0);
}

// ---------- LayerNorm: f32 in -> hi/lo bf16 split out ----------
__global__ __launch_bounds__(256) void ln_split_kernel(const float* __restrict__ x,
                                                       const float* __restrict__ g,
                                                       const float* __restrict__ b,
                                                       u16* __restrict__ yh,
                                                       u16* __restrict__ yl) {
    int row = blockIdx.x, tid = threadIdx.x;
    const float* xr = x + (size_t)row * DIMC;
    float v[3];
#pragma unroll
    for (int i = 0; i < 3; i++) v[i] = xr[tid + 256 * i];
    float s = v[0] + v[1] + v[2];
    float q = v[0]*v[0] + v[1]*v[1] + v[2]*v[2];
#pragma unroll
    for (int o = 32; o; o >>= 1) { s += __shfl_down(s, o, 64); q += __shfl_down(q, o, 64); }
    __shared__ float rs[4], rq[4];
    if ((tid & 63) == 0) { rs[tid >> 6] = s; rq[tid >> 6] = q; }
    __syncthreads();
    s = rs[0] + rs[1] + rs[2] + rs[3];
    q = rq[0] + rq[1] + rq[2] + rq[3];
    float mean = s * (1.f / DIMC);
    float var  = q * (1.f / DIMC) - mean * mean;
    float rstd = rsqrtf(var + 1e-5f);
#pragma unroll
    for (int i = 0; i < 3; i++) {
        int c = tid + 256 * i;
        float o = (v[i] - mean) * rstd * g[c] + b[c];
        u16 h = f2bf(o);
        yh[(size_t)row * DIMC + c] = h;
        yl[(size_t)row * DIMC + c] = f2bf(o - bf2f(h));
    }
}

// ---------- LayerNorm: f32 in -> bf16 out + f32 out (for MoE/router) ----------
__global__ __launch_bounds__(256) void ln_bf_kernel(const float* __restrict__ x,
                                                    const float* __restrict__ g,
                                                    const float* __restrict__ b,
                                                    u16* __restrict__ yb,
                                                    float* __restrict__ yf) {
    int row = blockIdx.x, tid = threadIdx.x;
    const float* xr = x + (size_t)row * DIMC;
    float v[3];
#pragma unroll
    for (int i = 0; i < 3; i++) v[i] = xr[tid + 256 * i];
    float s = v[0] + v[1] + v[2];
    float q = v[0]*v[0] + v[1]*v[1] + v[2]*v[2];
#pragma unroll
    for (int o = 32; o; o >>= 1) { s += __shfl_down(s, o, 64); q += __shfl_down(q, o, 64); }
    __shared__ float rs[4], rq[4];
    if ((tid & 63) == 0) { rs[tid >> 6] = s; rq[tid >> 6] = q; }
    __syncthreads();
    s = rs[0] + rs[1] + rs[2] + rs[3];
    q = rq[0] + rq[1] + rq[2] + rq[3];
    float mean = s * (1.f / DIMC);
    float var  = q * (1.f / DIMC) - mean * mean;
    float rstd = rsqrtf(var + 1e-5f);
#pragma unroll
    for (int i = 0; i < 3; i++) {
        int c = tid + 256 * i;
        float o = (v[i] - mean) * rstd * g[c] + b[c];
        yb[(size_t)row * DIMC + c] = f2bf(o);
        yf[(size_t)row * DIMC + c] = o;
    }
}

// ---------- transpose f32 src -> hi/lo bf16 dsts ----------
__global__ __launch_bounds__(256) void transpose_split_kernel(
    const float* __restrict__ src, u16* __restrict__ dh, u16* __restrict__ dl,
    int s_rs, int d_rs, long s_bs, long d_bs) {
    __shared__ u16 th[32][33], tl[32][33];
    int z = blockIdx.z;
    const float* sb = src + (long)z * s_bs;
    int r0 = blockIdx.y * 32, c0 = blockIdx.x * 32;
    int tx = threadIdx.x & 31, ty = threadIdx.x >> 5;
#pragma unroll
    for (int i = 0; i < 4; i++) {
        float v = sb[(size_t)(r0 + ty + 8 * i) * s_rs + c0 + tx];
        u16 h = f2bf(v);
        th[ty + 8 * i][tx] = h;
        tl[ty + 8 * i][tx] = f2bf(v - bf2f(h));
    }
    __syncthreads();
#pragma unroll
    for (int i = 0; i < 4; i++) {
        size_t o = (long)z * d_bs + (size_t)(c0 + ty + 8 * i) * d_rs + r0 + tx;
        dh[o] = th[tx][ty + 8 * i];
        dl[o] = tl[tx][ty + 8 * i];
    }
}

// ---------- transpose f32 src -> hi-only bf16 dst (MoE weights) ----------
__global__ __launch_bounds__(256) void transpose_f2b_kernel(
    const float* __restrict__ src, u16* __restrict__ dst,
    int s_rs, int d_rs, long s_bs, long d_bs) {
    __shared__ u16 tile[32][33];
    int z = blockIdx.z;
    const float* sb = src + (long)z * s_bs;
    int r0 = blockIdx.y * 32, c0 = blockIdx.x * 32;
    int tx = threadIdx.x & 31, ty = threadIdx.x >> 5;
#pragma unroll
    for (int i = 0; i < 4; i++)
        tile[ty + 8 * i][tx] = f2bf(sb[(size_t)(r0 + ty + 8 * i) * s_rs + c0 + tx]);
    __syncthreads();
#pragma unroll
    for (int i = 0; i < 4; i++)
        dst[(long)z * d_bs + (size_t)(c0 + ty + 8 * i) * d_rs + r0 + tx] = tile[tx][ty + 8 * i];
}

// ---------- bf16 batched transpose (V -> VT, run for hi and lo) ----------
__global__ __launch_bounds__(256) void transpose_b2b_kernel(
    const u16* __restrict__ src, u16* __restrict__ dst,
    int s_rs, int d_rs, long s_bs1, int s_n1, long s_bs2, long d_bs) {
    __shared__ u16 tile[32][33];
    int z = blockIdx.z;
    const u16* sb = src + (long)(z / s_n1) * s_bs1 + (long)(z % s_n1) * s_bs2;
    u16* db = dst + (long)z * d_bs;
    int r0 = blockIdx.y * 32, c0 = blockIdx.x * 32;
    int tx = threadIdx.x & 31, ty = threadIdx.x >> 5;
#pragma unroll
    for (int i = 0; i < 4; i++)
        tile[ty + 8 * i][tx] = sb[(size_t)(r0 + ty + 8 * i) * s_rs + c0 + tx];
    __syncthreads();
#pragma unroll
    for (int i = 0; i < 4; i++)
        db[(size_t)(c0 + ty + 8 * i) * d_rs + r0 + tx] = tile[tx][ty + 8 * i];
}

// ---------- split-precision GEMM: C = alpha*(A.Bt), A=Ah+Al, B=Bh+Bl ----------
// 3-term: ah.bh + ah.bl + al.bh  (rel err ~2^-17)
// EPI: 0 none ; 3 add f32 residual R.  OUT: 1 f32 store ; 2 hi/lo bf16 split store
template<int EPI, int OUT>
__global__ __launch_bounds__(256)
void gemm3_kernel(const u16* __restrict__ Ah, const u16* __restrict__ Al, int lda, long aBS,
                  const u16* __restrict__ Bh, const u16* __restrict__ Bl, int ldb, long bBS,
                  void* __restrict__ C0, void* __restrict__ C1, int ldc, long cBS,
                  int M, int N, int K, float alpha, const float* __restrict__ R) {
    __shared__ u16 Ash[128 * 32], Asl[128 * 32], Bsh[128 * 32], Bsl[128 * 32];
    int bm = blockIdx.y, bn = blockIdx.x, bz = blockIdx.z;
    int m0 = bm * 128, n0 = bn * 128;
    const u16* Ahb = Ah + (long)bz * aBS;
    const u16* Alb = Al + (long)bz * aBS;
    const u16* Bhb = Bh + (long)bz * bBS;
    const u16* Blb = Bl + (long)bz * bBS;
    int tid = threadIdx.x, wv = tid >> 6, ln = tid & 63;
    int quad = ln >> 4, l15 = ln & 15;
    int wm = wv & 1, wn = wv >> 1;
    f32x4 acc[4][4];
#pragma unroll
    for (int i = 0; i < 4; i++)
#pragma unroll
        for (int j = 0; j < 4; j++) acc[i][j] = (f32x4)0.f;
    int srow = ln >> 2, schk = (ln & 3) * 8;

    for (int k0 = 0; k0 < K; k0 += 32) {
#pragma unroll
        for (int j = 0; j < 2; j++) {
            int r = 32 * wv + 16 * j + srow;
            size_t ao = (size_t)(m0 + r) * lda + k0 + schk;
            async16(&Ash[(32 * wv + 16 * j) * 32], Ahb + ao);
            async16(&Asl[(32 * wv + 16 * j) * 32], Alb + ao);
            int gn = n0 + r; if (gn > N - 1) gn = N - 1;
            size_t bo = (size_t)gn * ldb + k0 + schk;
            async16(&Bsh[(32 * wv + 16 * j) * 32], Bhb + bo);
            async16(&Bsl[(32 * wv + 16 * j) * 32], Blb + bo);
        }
        __syncthreads();
        short8 ah[4], al4[4], bh[4], bl4[4];
#pragma unroll
        for (int mi = 0; mi < 4; mi++) {
            int off = (64 * wm + 16 * mi + l15) * 32 + quad * 8;
            ah[mi]  = *(const short8*)&Ash[off];
            al4[mi] = *(const short8*)&Asl[off];
        }
#pragma unroll
        for (int ni = 0; ni < 4; ni++) {
            int off = (64 * wn + 16 * ni + l15) * 32 + quad * 8;
            bh[ni]  = *(const short8*)&Bsh[off];
            bl4[ni] = *(const short8*)&Bsl[off];
        }
#pragma unroll
        for (int mi = 0; mi < 4; mi++)
#pragma unroll
            for (int ni = 0; ni < 4; ni++) {
                acc[mi][ni] = __builtin_amdgcn_mfma_f32_16x16x32_bf16(ah[mi],  bh[ni],  acc[mi][ni], 0, 0, 0);
                acc[mi][ni] = __builtin_amdgcn_mfma_f32_16x16x32_bf16(ah[mi],  bl4[ni], acc[mi][ni], 0, 0, 0);
                acc[mi][ni] = __builtin_amdgcn_mfma_f32_16x16x32_bf16(al4[mi], bh[ni],  acc[mi][ni], 0, 0, 0);
            }
        __syncthreads();
    }
#pragma unroll
    for (int mi = 0; mi < 4; mi++) {
#pragma unroll
        for (int r = 0; r < 4; r++) {
            int row = m0 + 64 * wm + 16 * mi + quad * 4 + r;
#pragma unroll
            for (int ni = 0; ni < 4; ni++) {
                int col = n0 + 64 * wn + 16 * ni + l15;
                if (col < N) {
                    size_t idx = (long)bz * cBS + (size_t)row * ldc + col;
                    float v = acc[mi][ni][r] * alpha;
                    if (EPI == 3) v += R[idx];
                    if (OUT == 1) ((float*)C0)[idx] = v;
                    else {
                        u16 h = f2bf(v);
                        ((u16*)C0)[idx] = h;
                        ((u16*)C1)[idx] = f2bf(v - bf2f(h));
                    }
                }
            }
        }
    }
}

// ---------- plain bf16 GEMM for MoE experts ----------
// EPI: 0 none ; 2 gelu-exact.  MOE segment lookup.  OUTF: 0 bf16 ; 1 f32
template<int EPI, int OUTF>
__global__ __launch_bounds__(256)
void gemm_moe_kernel(const u16* __restrict__ A, int lda,
                     const u16* __restrict__ B, int ldb,
                     void* __restrict__ Cv, int ldc,
                     int N, int K,
                     const int* __restrict__ seg, long expStride) {
    __shared__ u16 As[128 * 32];
    __shared__ u16 Bs[128 * 32];
    int m0 = blockIdx.y * 128, n0 = blockIdx.x * 128;
    if (m0 >= seg[8]) return;
    int e = 0;
#pragma unroll
    for (int i = 1; i < 8; i++) if (m0 >= seg[i]) e = i;
    const u16* Bp = B + (long)e * expStride;
    int tid = threadIdx.x, wv = tid >> 6, ln = tid & 63;
    int quad = ln >> 4, l15 = ln & 15;
    int wm = wv & 1, wn = wv >> 1;
    f32x4 acc[4][4];
#pragma unroll
    for (int i = 0; i < 4; i++)
#pragma unroll
        for (int j = 0; j < 4; j++) acc[i][j] = (f32x4)0.f;
    int srow = ln >> 2, schk = (ln & 3) * 8;
    for (int k0 = 0; k0 < K; k0 += 32) {
#pragma unroll
        for (int j = 0; j < 2; j++) {
            int r = 32 * wv + 16 * j + srow;
            async16(&As[(32 * wv + 16 * j) * 32], A + (size_t)(m0 + r) * lda + k0 + schk);
            async16(&Bs[(32 * wv + 16 * j) * 32], Bp + (size_t)(n0 + r) * ldb + k0 + schk);
        }
        __syncthreads();
        short8 af[4], bfr[4];
#pragma unroll
        for (int mi = 0; mi < 4; mi++)
            af[mi] = *(const short8*)&As[(64 * wm + 16 * mi + l15) * 32 + quad * 8];
#pragma unroll
        for (int ni = 0; ni < 4; ni++)
            bfr[ni] = *(const short8*)&Bs[(64 * wn + 16 * ni + l15) * 32 + quad * 8];
#pragma unroll
        for (int mi = 0; mi < 4; mi++)
#pragma unroll
            for (int ni = 0; ni < 4; ni++)
                acc[mi][ni] = __builtin_amdgcn_mfma_f32_16x16x32_bf16(af[mi], bfr[ni], acc[mi][ni], 0, 0, 0);
        __syncthreads();
    }
#pragma unroll
    for (int mi = 0; mi < 4; mi++) {
#pragma unroll
        for (int r = 0; r < 4; r++) {
            int row = m0 + 64 * wm + 16 * mi + quad * 4 + r;
#pragma unroll
            for (int ni = 0; ni < 4; ni++) {
                int col = n0 + 64 * wn + 16 * ni + l15;
                float v = acc[mi][ni][r];
                if (EPI == 2) v = 0.5f * v * (1.f + erff(v * 0.70710678118654752f));
                size_t idx = (size_t)row * ldc + col;
                if (OUTF) ((float*)Cv)[idx] = v;
                else      ((u16*)Cv)[idx] = f2bf(v);
            }
        }
    }
}

// ---------- softmax over f32 rows of 1024; writes P hi/lo in place ----------
__global__ __launch_bounds__(256) void softmax_split_kernel(float* __restrict__ S) {
    size_t row = blockIdx.x;
    float* p = S + row * (size_t)SEQ;
    u16* ph = (u16*)p;         // first 2KB of the 4KB row
    u16* pl = (u16*)p + SEQ;   // second 2KB
    int tid = threadIdx.x;
    float v[4];
#pragma unroll
    for (int i = 0; i < 4; i++) v[i] = p[tid + 256 * i];
    float m = fmaxf(fmaxf(v[0], v[1]), fmaxf(v[2], v[3]));
#pragma unroll
    for (int o = 32; o; o >>= 1) m = fmaxf(m, __shfl_down(m, o, 64));
    __shared__ float red[4], red2[4];
    if ((tid & 63) == 0) red[tid >> 6] = m;
    __syncthreads();
    m = fmaxf(fmaxf(red[0], red[1]), fmaxf(red[2], red[3]));
    float e[4], s = 0.f;
#pragma unroll
    for (int i = 0; i < 4; i++) { e[i] = expf(v[i] - m); s += e[i]; }
#pragma unroll
    for (int o = 32; o; o >>= 1) s += __shfl_down(s, o, 64);
    if ((tid & 63) == 0) red2[tid >> 6] = s;
    __syncthreads();
    s = red2[0] + red2[1] + red2[2] + red2[3];
    float inv = 1.f / s;
#pragma unroll
    for (int i = 0; i < 4; i++) {
        int c = tid + 256 * i;
        float w = e[i] * inv;
        u16 h = f2bf(w);
        ph[c] = h;
        pl[c] = f2bf(w - bf2f(h));
    }
}

// ---------- router: f32 logits, top-2, softmax weights ----------
__global__ __launch_bounds__(256) void router_kernel(const float* __restrict__ h2f,
                                                     const float* __restrict__ Wr,
                                                     int* __restrict__ topk_idx,
                                                     float* __restrict__ topk_w,
                                                     int* __restrict__ counts) {
    int t = blockIdx.x, tid = threadIdx.x;
    __shared__ float part[256 * 8];
    float l[8];
#pragma unroll
    for (int e = 0; e < 8; e++) l[e] = 0.f;
    const float* xr = h2f + (size_t)t * DIMC;
#pragma unroll
    for (int i = 0; i < 3; i++) {
        int c = tid + 256 * i;
        float xv = xr[c];
        const float* wr = Wr + (size_t)c * NEXP;
#pragma unroll
        for (int e = 0; e < 8; e++) l[e] += xv * wr[e];
    }
#pragma unroll
    for (int e = 0; e < 8; e++) part[tid * 8 + e] = l[e];
    for (int s = 128; s; s >>= 1) {
        __syncthreads();
        if (tid < s)
#pragma unroll
            for (int e = 0; e < 8; e++) part[tid * 8 + e] += part[(tid + s) * 8 + e];
    }
    __syncthreads();
    if (tid == 0) {
        float lg[8];
#pragma unroll
        for (int e = 0; e < 8; e++) lg[e] = part[e];
        int i0 = 0;
        for (int e = 1; e < 8; e++) if (lg[e] > lg[i0]) i0 = e;   // ties -> lowest idx
        int i1 = -1;
        for (int e = 0; e < 8; e++) if (e != i0 && (i1 < 0 || lg[e] > lg[i1])) i1 = e;
        float w1 = expf(lg[i1] - lg[i0]);
        float den = 1.f + w1;
        topk_idx[2 * t] = i0; topk_idx[2 * t + 1] = i1;
        topk_w[2 * t] = 1.f / den;  topk_w[2 * t + 1] = w1 / den;
        atomicAdd(&counts[i0], 1); atomicAdd(&counts[i1], 1);
    }
}

__global__ void offsets_kernel(const int* __restrict__ counts,
                               int* __restrict__ seg, int* __restrict__ cursor) {
    if (threadIdx.x == 0 && blockIdx.x == 0) {
        int off = 0;
        for (int e = 0; e < 8; e++) {
            seg[e] = off; cursor[e] = off;
            off += ((counts[e] + 127) / 128) * 128;
        }
        seg[8] = off;
    }
}

__global__ __launch_bounds__(256) void build_perm_kernel(
    const int* __restrict__ topk_idx, const float* __restrict__ topk_w,
    int* __restrict__ cursor, int* __restrict__ perm,
    float* __restrict__ gatew, int* __restrict__ slot_of) {
    int t = blockIdx.x * 256 + threadIdx.x;
    if (t >= TOK) return;
#pragma unroll
    for (int j = 0; j < 2; j++) {
        int e = topk_idx[2 * t + j];
        int slot = atomicAdd(&cursor[e], 1);
        perm[slot] = t;
        gatew[slot] = topk_w[2 * t + j];
        slot_of[2 * t + j] = slot;
    }
}

__global__ __launch_bounds__(192) void gather_kernel(const u16* __restrict__ h2,
                                                     const int* __restrict__ perm,
                                                     u16* __restrict__ xg) {
    int slot = blockIdx.x;
    int t = perm[slot];  // pad slots -> token 0 (memset perm), harmless
    const uint2* s = (const uint2*)(h2 + (size_t)t * DIMC);
    uint2* d = (uint2*)(xg + (size_t)slot * DIMC);
    d[threadIdx.x] = s[threadIdx.x];
}

__global__ __launch_bounds__(192) void combine_kernel(
    const float* __restrict__ x1, const float* __restrict__ yg,
    const float* __restrict__ gatew, const int* __restrict__ slot_of,
    float* __restrict__ out) {
    int t = blockIdx.x;
    int s0 = slot_of[2 * t], s1 = slot_of[2 * t + 1];
    float w0 = gatew[s0], w1 = gatew[s1];
    int c = threadIdx.x * 4;
    const float* xr = x1 + (size_t)t * DIMC;
    const float* y0 = yg + (size_t)s0 * DIMC;
    const float* y1 = yg + (size_t)s1 * DIMC;
    float* orow = out + (size_t)t * DIMC;
#pragma unroll
    for (int k = 0; k < 4; k++)
        orow[c + k] = xr[c + k] + w0 * y0[c + k] + w1 * y1[c + k];
}

// ---------- launcher ----------
extern "C" void kernel_launch(void* const* d_in, const int* in_sizes, int n_in,
                              void* d_out, int out_size, void* d_ws, size_t ws_size,
                              hipStream_t stream) {
    const float* x       = (const float*)d_in[0];
    const float* Wqkv    = (const float*)d_in[1];
    const float* Wproj   = (const float*)d_in[2];
    const float* Wrouter = (const float*)d_in[3];
    const float* W1      = (const float*)d_in[4];
    const float* W2      = (const float*)d_in[5];
    const float* ln1g    = (const float*)d_in[6];
    const float* ln1b    = (const float*)d_in[7];
    const float* ln2g    = (const float*)d_in[8];
    const float* ln2b    = (const float*)d_in[9];
    float* out = (float*)d_out;
    char* ws = (char*)d_ws;

    // ---- layout: x1 | rout | pool (phase-A / phase-B overlays) ----
    const size_t o_x1   = 0;           // 12582912 B f32 residual
    const size_t o_rout = 12582912;    // 262144 B
    const size_t P      = 12845056;    // pool base
    const size_t WS_REQ = 177995776;   // == P + 165150720 (proven to fit)
    if (ws_size < WS_REQ) return;      // signature: absmax == max|ref| (~5.72)

    float* x1 = (float*)(ws + o_x1);
    // phase A (attention) inside pool:
    float* Sc    = (float*)(ws + P);                 // 50331648 (per-batch scores / P hi+lo)
    u16*   qkvh  = (u16*)(ws + P + 50331648);        // 18874368
    u16*   qkvl  = (u16*)(ws + P + 69206016);        // 18874368
    u16*   VTh   = (u16*)(ws + P + 88080384);        // 6291456
    u16*   VTl   = (u16*)(ws + P + 94371840);        // 6291456
    u16*   atth  = (u16*)(ws + P + 100663296);       // 6291456
    u16*   attl  = (u16*)(ws + P + 106954752);       // 6291456
    u16*   h1h   = (u16*)(ws + P + 113246208);       // 6291456
    u16*   h1l   = (u16*)(ws + P + 119537664);       // 6291456
    u16*   Wqh   = (u16*)(ws + P + 125829120);       // 3538944
    u16*   Wql   = (u16*)(ws + P + 129368064);       // 3538944
    u16*   Wph   = (u16*)(ws + P + 132907008);       // 1179648
    u16*   Wpl   = (u16*)(ws + P + 134086656);       // 1179648 -> ends P+135266304
    // phase B (MoE) overlays:
    u16*   W1T   = (u16*)(ws + P);                   // 37748736
    u16*   W2T   = (u16*)(ws + P + 37748736);        // 37748736
    u16*   h2    = (u16*)(ws + P + 75497472);        // 6291456
    float* h2f   = (float*)(ws + P + 81788928);      // 12582912
    u16*   xg    = (u16*)(ws + P + 94371840);        // 14155776
    u16*   hid   = (u16*)(ws + P + 108527616);       // 56623104 -> ends P+165150720
    float* yg    = (float*)(ws + P + 75497472);      // 28311552, overlays h2/h2f/xg

    int*   counts   = (int*)(ws + o_rout + 0);
    int*   seg      = (int*)(ws + o_rout + 64);
    int*   cursor   = (int*)(ws + o_rout + 128);
    int*   topk_idx = (int*)(ws + o_rout + 1024);
    float* topk_w   = (float*)(ws + o_rout + 34816);
    int*   perm     = (int*)(ws + o_rout + 68608);
    float* gatew    = (float*)(ws + o_rout + 106496);
    int*   slot_of  = (int*)(ws + o_rout + 144384);

    const long EXPSTR = (long)DIMC * FFC;

    // ===== Phase A: attention (bf16x3 split precision) =====
    transpose_split_kernel<<<dim3(NQKVC/32, DIMC/32, 1), 256, 0, stream>>>(
        Wqkv, Wqh, Wql, NQKVC, DIMC, 0, 0);
    transpose_split_kernel<<<dim3(DIMC/32, DIMC/32, 1), 256, 0, stream>>>(
        Wproj, Wph, Wpl, DIMC, DIMC, 0, 0);
    ln_split_kernel<<<TOK, 256, 0, stream>>>(x, ln1g, ln1b, h1h, h1l);
    // qkv = h1 @ Wqkv  -> hi/lo split out
    gemm3_kernel<0,2><<<dim3(NQKVC/128, TOK/128, 1), 256, 0, stream>>>(
        h1h, h1l, DIMC, 0, Wqh, Wql, DIMC, 0,
        qkvh, qkvl, NQKVC, 0, TOK, NQKVC, DIMC, 1.f, nullptr);
    // VT[b,h][d][t] = V[b,h][t][d]  (hi and lo)
    transpose_b2b_kernel<<<dim3(HDIM/32, SEQ/32, NBATCH*NHEAD), 256, 0, stream>>>(
        qkvh + 2 * DIMC, VTh, NQKVC, SEQ, (long)SEQ * NQKVC, NHEAD, (long)HDIM, (long)HDIM * SEQ);
    transpose_b2b_kernel<<<dim3(HDIM/32, SEQ/32, NBATCH*NHEAD), 256, 0, stream>>>(
        qkvl + 2 * DIMC, VTl, NQKVC, SEQ, (long)SEQ * NQKVC, NHEAD, (long)HDIM, (long)HDIM * SEQ);
    for (int b = 0; b < NBATCH; b++) {
        const u16* qbh = qkvh + (size_t)b * SEQ * NQKVC;
        const u16* qbl = qkvl + (size_t)b * SEQ * NQKVC;
        // Sc[h][q][k] = 0.125 * Q.K^T  (f32 out)
        gemm3_kernel<0,1><<<dim3(SEQ/128, SEQ/128, NHEAD), 256, 0, stream>>>(
            qbh, qbl, NQKVC, (long)HDIM,
            qbh + DIMC, qbl + DIMC, NQKVC, (long)HDIM,
            Sc, nullptr, SEQ, (long)SEQ * SEQ,
            SEQ, SEQ, HDIM, 0.125f, nullptr);
        softmax_split_kernel<<<NHEAD * SEQ, 256, 0, stream>>>(Sc);
        // O[q][d] = P.V  -> hi/lo split out.  P rows live inside Sc (u16 ld 2048)
        gemm3_kernel<0,2><<<dim3(1, SEQ/128, NHEAD), 256, 0, stream>>>(
            (const u16*)Sc, (const u16*)Sc + SEQ, 2 * SEQ, (long)SEQ * 2 * SEQ,
            VTh + (size_t)b * NHEAD * HDIM * SEQ, VTl + (size_t)b * NHEAD * HDIM * SEQ,
            SEQ, (long)HDIM * SEQ,
            atth + (size_t)b * SEQ * DIMC, attl + (size_t)b * SEQ * DIMC, DIMC, (long)HDIM,
            SEQ, HDIM, SEQ, 1.f, nullptr);
    }
    // x1 = x + attno @ Wproj  (f32 out)
    gemm3_kernel<3,1><<<dim3(DIMC/128, TOK/128, 1), 256, 0, stream>>>(
        atth, attl, DIMC, 0, Wph, Wpl, DIMC, 0,
        x1, nullptr, DIMC, 0, TOK, DIMC, DIMC, 1.f, x);

    // ===== Phase B: MoE (overlays phase-A pool) =====
    transpose_f2b_kernel<<<dim3(FFC/32, DIMC/32, NEXP), 256, 0, stream>>>(
        W1, W1T, FFC, DIMC, EXPSTR, EXPSTR);
    transpose_f2b_kernel<<<dim3(DIMC/32, FFC/32, NEXP), 256, 0, stream>>>(
        W2, W2T, DIMC, FFC, EXPSTR, EXPSTR);
    ln_bf_kernel<<<TOK, 256, 0, stream>>>(x1, ln2g, ln2b, h2, h2f);
    (void)hipMemsetAsync(ws + o_rout, 0, 262144, stream);
    router_kernel<<<TOK, 256, 0, stream>>>(h2f, Wrouter, topk_idx, topk_w, counts);
    offsets_kernel<<<1, 64, 0, stream>>>(counts, seg, cursor);
    build_perm_kernel<<<16, 256, 0, stream>>>(topk_idx, topk_w, cursor, perm, gatew, slot_of);
    gather_kernel<<<SLOTS, 192, 0, stream>>>(h2, perm, xg);
    // hid = gelu(xg @ W1[e])  bf16 out
    gemm_moe_kernel<2,0><<<dim3(FFC/128, SLOTS/128, 1), 256, 0, stream>>>(
        xg, DIMC, W1T, DIMC, hid, FFC, FFC, DIMC, seg, EXPSTR);
    // yg = hid @ W2[e]  f32 out
    gemm_moe_kernel<0,1><<<dim3(DIMC/128, SLOTS/128, 1), 256, 0, stream>>>(
        hid, FFC, W2T, FFC, yg, DIMC, DIMC, FFC, seg, EXPSTR);
    combine_kernel<<<TOK, 192, 0, stream>>>(x1, yg, gatew, slot_of, out);

    (void)in_sizes; (void)n_in; (void)out_size;
}

// Round 4
// 888.829 us; speedup vs baseline: 1.1459x; 1.1459x over previous
//
#include <hip/hip_runtime.h>
#include <math.h>

typedef unsigned short u16;
typedef __attribute__((ext_vector_type(8))) short short8;
typedef __attribute__((ext_vector_type(4))) float f32x4;

#define DIMC   768
#define TOK    4096
#define NQKVC  2304
#define FFC    3072
#define NEXP   8
#define NHEAD  12
#define HDIM   64
#define SEQ    1024
#define NBATCH 4
#define SLOTS  9216   // 8192 + per-expert 128-pad slack (max 9208)

// ---------- bf16 helpers ----------
__device__ __forceinline__ float bf2f(u16 v) {
    unsigned int u = ((unsigned int)v) << 16;
    float f; __builtin_memcpy(&f, &u, 4); return f;
}
__device__ __forceinline__ u16 f2bf(float f) {
    unsigned int u; __builtin_memcpy(&u, &f, 4);
    u = (u + 0x7fffu + ((u >> 16) & 1u)) >> 16;
    return (u16)u;
}

// fast gelu-exact: erf via A&S 7.1.26 (|eps|<=1.5e-7), ~14 VALU incl v_exp
__device__ __forceinline__ float fast_gelu(float v) {
    float x = fabsf(v) * 0.70710678118654752f;
    float t = __builtin_amdgcn_rcpf(1.f + 0.3275911f * x);
    float y = t * (0.254829592f + t * (-0.284496736f + t * (1.421413741f +
              t * (-1.453152027f + t * 1.061405429f))));
    float er = 1.f - y * __expf(-x * x);
    er = (v < 0.f) ? -er : er;
    return 0.5f * v * (1.f + er);
}

// async global->LDS, 16B per lane. lds base must be wave-uniform; HW adds lane*16.
__device__ __forceinline__ void async16(u16* lds, const u16* gp) {
    __builtin_amdgcn_global_load_lds(
        (const __attribute__((address_space(1))) unsigned int*)gp,
        (__attribute__((address_space(3))) unsigned int*)lds, 16, 0, 0);
}

// ---------- LayerNorm: f32 in -> hi/lo bf16 split out ----------
__global__ __launch_bounds__(256) void ln_split_kernel(const float* __restrict__ x,
                                                       const float* __restrict__ g,
                                                       const float* __restrict__ b,
                                                       u16* __restrict__ yh,
                                                       u16* __restrict__ yl) {
    int row = blockIdx.x, tid = threadIdx.x;
    const float* xr = x + (size_t)row * DIMC;
    float v[3];
#pragma unroll
    for (int i = 0; i < 3; i++) v[i] = xr[tid + 256 * i];
    float s = v[0] + v[1] + v[2];
    float q = v[0]*v[0] + v[1]*v[1] + v[2]*v[2];
#pragma unroll
    for (int o = 32; o; o >>= 1) { s += __shfl_down(s, o, 64); q += __shfl_down(q, o, 64); }
    __shared__ float rs[4], rq[4];
    if ((tid & 63) == 0) { rs[tid >> 6] = s; rq[tid >> 6] = q; }
    __syncthreads();
    s = rs[0] + rs[1] + rs[2] + rs[3];
    q = rq[0] + rq[1] + rq[2] + rq[3];
    float mean = s * (1.f / DIMC);
    float var  = q * (1.f / DIMC) - mean * mean;
    float rstd = rsqrtf(var + 1e-5f);
#pragma unroll
    for (int i = 0; i < 3; i++) {
        int c = tid + 256 * i;
        float o = (v[i] - mean) * rstd * g[c] + b[c];
        u16 h = f2bf(o);
        yh[(size_t)row * DIMC + c] = h;
        yl[(size_t)row * DIMC + c] = f2bf(o - bf2f(h));
    }
}

// ---------- LayerNorm: f32 in -> bf16 out + f32 out (for MoE/router) ----------
__global__ __launch_bounds__(256) void ln_bf_kernel(const float* __restrict__ x,
                                                    const float* __restrict__ g,
                                                    const float* __restrict__ b,
                                                    u16* __restrict__ yb,
                                                    float* __restrict__ yf) {
    int row = blockIdx.x, tid = threadIdx.x;
    const float* xr = x + (size_t)row * DIMC;
    float v[3];
#pragma unroll
    for (int i = 0; i < 3; i++) v[i] = xr[tid + 256 * i];
    float s = v[0] + v[1] + v[2];
    float q = v[0]*v[0] + v[1]*v[1] + v[2]*v[2];
#pragma unroll
    for (int o = 32; o; o >>= 1) { s += __shfl_down(s, o, 64); q += __shfl_down(q, o, 64); }
    __shared__ float rs[4], rq[4];
    if ((tid & 63) == 0) { rs[tid >> 6] = s; rq[tid >> 6] = q; }
    __syncthreads();
    s = rs[0] + rs[1] + rs[2] + rs[3];
    q = rq[0] + rq[1] + rq[2] + rq[3];
    float mean = s * (1.f / DIMC);
    float var  = q * (1.f / DIMC) - mean * mean;
    float rstd = rsqrtf(var + 1e-5f);
#pragma unroll
    for (int i = 0; i < 3; i++) {
        int c = tid + 256 * i;
        float o = (v[i] - mean) * rstd * g[c] + b[c];
        yb[(size_t)row * DIMC + c] = f2bf(o);
        yf[(size_t)row * DIMC + c] = o;
    }
}

// ---------- f32 src -> hi/lo bf16 split (elementwise) ----------
__global__ __launch_bounds__(256) void split_hl_kernel(const float* __restrict__ src,
                                                       u16* __restrict__ dh,
                                                       u16* __restrict__ dl) {
    size_t i = ((size_t)blockIdx.x * 256 + threadIdx.x) * 4;
#pragma unroll
    for (int k = 0; k < 4; k++) {
        float v = src[i + k];
        u16 h = f2bf(v);
        dh[i + k] = h;
        dl[i + k] = f2bf(v - bf2f(h));
    }
}

// ---------- transpose f32 src -> hi/lo bf16 dsts ----------
__global__ __launch_bounds__(256) void transpose_split_kernel(
    const float* __restrict__ src, u16* __restrict__ dh, u16* __restrict__ dl,
    int s_rs, int d_rs, long s_bs, long d_bs) {
    __shared__ u16 th[32][33], tl[32][33];
    int z = blockIdx.z;
    const float* sb = src + (long)z * s_bs;
    int r0 = blockIdx.y * 32, c0 = blockIdx.x * 32;
    int tx = threadIdx.x & 31, ty = threadIdx.x >> 5;
#pragma unroll
    for (int i = 0; i < 4; i++) {
        float v = sb[(size_t)(r0 + ty + 8 * i) * s_rs + c0 + tx];
        u16 h = f2bf(v);
        th[ty + 8 * i][tx] = h;
        tl[ty + 8 * i][tx] = f2bf(v - bf2f(h));
    }
    __syncthreads();
#pragma unroll
    for (int i = 0; i < 4; i++) {
        size_t o = (long)z * d_bs + (size_t)(c0 + ty + 8 * i) * d_rs + r0 + tx;
        dh[o] = th[tx][ty + 8 * i];
        dl[o] = tl[tx][ty + 8 * i];
    }
}

// ---------- transpose f32 src -> hi-only bf16 dst (MoE weights) ----------
__global__ __launch_bounds__(256) void transpose_f2b_kernel(
    const float* __restrict__ src, u16* __restrict__ dst,
    int s_rs, int d_rs, long s_bs, long d_bs) {
    __shared__ u16 tile[32][33];
    int z = blockIdx.z;
    const float* sb = src + (long)z * s_bs;
    int r0 = blockIdx.y * 32, c0 = blockIdx.x * 32;
    int tx = threadIdx.x & 31, ty = threadIdx.x >> 5;
#pragma unroll
    for (int i = 0; i < 4; i++)
        tile[ty + 8 * i][tx] = f2bf(sb[(size_t)(r0 + ty + 8 * i) * s_rs + c0 + tx]);
    __syncthreads();
#pragma unroll
    for (int i = 0; i < 4; i++)
        dst[(long)z * d_bs + (size_t)(c0 + ty + 8 * i) * d_rs + r0 + tx] = tile[tx][ty + 8 * i];
}

// ---------- bf16 batched transpose (V -> VT, run for hi and lo) ----------
__global__ __launch_bounds__(256) void transpose_b2b_kernel(
    const u16* __restrict__ src, u16* __restrict__ dst,
    int s_rs, int d_rs, long s_bs1, int s_n1, long s_bs2, long d_bs) {
    __shared__ u16 tile[32][33];
    int z = blockIdx.z;
    const u16* sb = src + (long)(z / s_n1) * s_bs1 + (long)(z % s_n1) * s_bs2;
    u16* db = dst + (long)z * d_bs;
    int r0 = blockIdx.y * 32, c0 = blockIdx.x * 32;
    int tx = threadIdx.x & 31, ty = threadIdx.x >> 5;
#pragma unroll
    for (int i = 0; i < 4; i++)
        tile[ty + 8 * i][tx] = sb[(size_t)(r0 + ty + 8 * i) * s_rs + c0 + tx];
    __syncthreads();
#pragma unroll
    for (int i = 0; i < 4; i++)
        db[(size_t)(c0 + ty + 8 * i) * d_rs + r0 + tx] = tile[tx][ty + 8 * i];
}

// ---------- split-precision GEMM: C = alpha*(A.Bt), A=Ah+Al, B=Bh+Bl ----------
// 3-term: ah.bh + ah.bl + al.bh  (rel err ~2^-17)
// EPI: 0 none ; 3 add f32 residual R.  OUT: 1 f32 store ; 2 hi/lo bf16 split store
template<int EPI, int OUT>
__global__ __launch_bounds__(256)
void gemm3_kernel(const u16* __restrict__ Ah, const u16* __restrict__ Al, int lda, long aBS,
                  const u16* __restrict__ Bh, const u16* __restrict__ Bl, int ldb, long bBS,
                  void* __restrict__ C0, void* __restrict__ C1, int ldc, long cBS,
                  int M, int N, int K, float alpha, const float* __restrict__ R) {
    __shared__ u16 Ash[128 * 32], Asl[128 * 32], Bsh[128 * 32], Bsl[128 * 32];
    int bm = blockIdx.y, bn = blockIdx.x, bz = blockIdx.z;
    int m0 = bm * 128, n0 = bn * 128;
    const u16* Ahb = Ah + (long)bz * aBS;
    const u16* Alb = Al + (long)bz * aBS;
    const u16* Bhb = Bh + (long)bz * bBS;
    const u16* Blb = Bl + (long)bz * bBS;
    int tid = threadIdx.x, wv = tid >> 6, ln = tid & 63;
    int quad = ln >> 4, l15 = ln & 15;
    int wm = wv & 1, wn = wv >> 1;
    f32x4 acc[4][4];
#pragma unroll
    for (int i = 0; i < 4; i++)
#pragma unroll
        for (int j = 0; j < 4; j++) acc[i][j] = (f32x4)0.f;
    int srow = ln >> 2, schk = (ln & 3) * 8;

    for (int k0 = 0; k0 < K; k0 += 32) {
#pragma unroll
        for (int j = 0; j < 2; j++) {
            int r = 32 * wv + 16 * j + srow;
            size_t ao = (size_t)(m0 + r) * lda + k0 + schk;
            async16(&Ash[(32 * wv + 16 * j) * 32], Ahb + ao);
            async16(&Asl[(32 * wv + 16 * j) * 32], Alb + ao);
            size_t bo = (size_t)(n0 + r) * ldb + k0 + schk;
            async16(&Bsh[(32 * wv + 16 * j) * 32], Bhb + bo);
            async16(&Bsl[(32 * wv + 16 * j) * 32], Blb + bo);
        }
        __syncthreads();
        short8 ah[4], al4[4], bh[4], bl4[4];
#pragma unroll
        for (int mi = 0; mi < 4; mi++) {
            int off = (64 * wm + 16 * mi + l15) * 32 + quad * 8;
            ah[mi]  = *(const short8*)&Ash[off];
            al4[mi] = *(const short8*)&Asl[off];
        }
#pragma unroll
        for (int ni = 0; ni < 4; ni++) {
            int off = (64 * wn + 16 * ni + l15) * 32 + quad * 8;
            bh[ni]  = *(const short8*)&Bsh[off];
            bl4[ni] = *(const short8*)&Bsl[off];
        }
#pragma unroll
        for (int mi = 0; mi < 4; mi++)
#pragma unroll
            for (int ni = 0; ni < 4; ni++) {
                acc[mi][ni] = __builtin_amdgcn_mfma_f32_16x16x32_bf16(ah[mi],  bh[ni],  acc[mi][ni], 0, 0, 0);
                acc[mi][ni] = __builtin_amdgcn_mfma_f32_16x16x32_bf16(ah[mi],  bl4[ni], acc[mi][ni], 0, 0, 0);
                acc[mi][ni] = __builtin_amdgcn_mfma_f32_16x16x32_bf16(al4[mi], bh[ni],  acc[mi][ni], 0, 0, 0);
            }
        __syncthreads();
    }
#pragma unroll
    for (int mi = 0; mi < 4; mi++) {
#pragma unroll
        for (int r = 0; r < 4; r++) {
            int row = m0 + 64 * wm + 16 * mi + quad * 4 + r;
#pragma unroll
            for (int ni = 0; ni < 4; ni++) {
                int col = n0 + 64 * wn + 16 * ni + l15;
                size_t idx = (long)bz * cBS + (size_t)row * ldc + col;
                float v = acc[mi][ni][r] * alpha;
                if (EPI == 3) v += R[idx];
                if (OUT == 1) ((float*)C0)[idx] = v;
                else {
                    u16 h = f2bf(v);
                    ((u16*)C0)[idx] = h;
                    ((u16*)C1)[idx] = f2bf(v - bf2f(h));
                }
            }
        }
    }
}

// ---------- PV: split-precision, 64x64 tile, split-K, atomic f32 out ----------
// grid: x=kz(4), y=qtile(SEQ/64), z=head.  O[q][h*64+d] += P[h,q,:].V[h,:,d]
__global__ __launch_bounds__(256)
void gemm3_pv_kernel(const u16* __restrict__ Ph,   // u16 view of Sc; row ld 2*SEQ
                     const u16* __restrict__ VTh_, const u16* __restrict__ VTl_,
                     float* __restrict__ attf, int b) {
    __shared__ u16 Ash[64 * 32], Asl[64 * 32], Bsh[64 * 32], Bsl[64 * 32];
    int kz = blockIdx.x, qt = blockIdx.y, h = blockIdx.z;
    int tid = threadIdx.x, wv = tid >> 6, ln = tid & 63;
    int quad = ln >> 4, l15 = ln & 15;
    const u16* Ah = Ph + (size_t)h * SEQ * 2 * SEQ;
    const u16* Al = Ah + SEQ;
    const u16* Bh = VTh_ + (size_t)h * HDIM * SEQ;
    const u16* Bl = VTl_ + (size_t)h * HDIM * SEQ;
    int m0 = qt * 64;
    f32x4 acc[4];
#pragma unroll
    for (int i = 0; i < 4; i++) acc[i] = (f32x4)0.f;
    int srow = ln >> 2, schk = (ln & 3) * 8;
    int kbase = kz * (SEQ / 4);
    for (int k0 = kbase; k0 < kbase + SEQ / 4; k0 += 32) {
        int r = 16 * wv + srow;
        async16(&Ash[(16 * wv) * 32], Ah + (size_t)(m0 + r) * 2 * SEQ + k0 + schk);
        async16(&Asl[(16 * wv) * 32], Al + (size_t)(m0 + r) * 2 * SEQ + k0 + schk);
        async16(&Bsh[(16 * wv) * 32], Bh + (size_t)r * SEQ + k0 + schk);
        async16(&Bsl[(16 * wv) * 32], Bl + (size_t)r * SEQ + k0 + schk);
        __syncthreads();
        short8 a_h = *(const short8*)&Ash[(16 * wv + l15) * 32 + quad * 8];
        short8 a_l = *(const short8*)&Asl[(16 * wv + l15) * 32 + quad * 8];
#pragma unroll
        for (int ni = 0; ni < 4; ni++) {
            short8 b_h = *(const short8*)&Bsh[(16 * ni + l15) * 32 + quad * 8];
            short8 b_l = *(const short8*)&Bsl[(16 * ni + l15) * 32 + quad * 8];
            acc[ni] = __builtin_amdgcn_mfma_f32_16x16x32_bf16(a_h, b_h, acc[ni], 0, 0, 0);
            acc[ni] = __builtin_amdgcn_mfma_f32_16x16x32_bf16(a_h, b_l, acc[ni], 0, 0, 0);
            acc[ni] = __builtin_amdgcn_mfma_f32_16x16x32_bf16(a_l, b_h, acc[ni], 0, 0, 0);
        }
        __syncthreads();
    }
#pragma unroll
    for (int ni = 0; ni < 4; ni++)
#pragma unroll
        for (int r = 0; r < 4; r++) {
            int q = m0 + 16 * wv + quad * 4 + r;
            int d = h * HDIM + 16 * ni + l15;
            atomicAdd(&attf[((size_t)b * SEQ + q) * DIMC + d], acc[ni][r]);
        }
}

// ---------- plain bf16 GEMM 128x128 for MoE GEMM1 (gelu epilogue) ----------
template<int EPI, int OUTF>   // EPI: 0 none, 2 gelu ; OUTF: 0 bf16, 1 f32
__global__ __launch_bounds__(256)
void gemm_moe_kernel(const u16* __restrict__ A, int lda,
                     const u16* __restrict__ B, int ldb,
                     void* __restrict__ Cv, int ldc,
                     int N, int K,
                     const int* __restrict__ seg, long expStride) {
    __shared__ u16 As[128 * 32];
    __shared__ u16 Bs[128 * 32];
    int m0 = blockIdx.y * 128, n0 = blockIdx.x * 128;
    if (m0 >= seg[8]) return;
    int e = 0;
#pragma unroll
    for (int i = 1; i < 8; i++) if (m0 >= seg[i]) e = i;
    const u16* Bp = B + (long)e * expStride;
    int tid = threadIdx.x, wv = tid >> 6, ln = tid & 63;
    int quad = ln >> 4, l15 = ln & 15;
    int wm = wv & 1, wn = wv >> 1;
    f32x4 acc[4][4];
#pragma unroll
    for (int i = 0; i < 4; i++)
#pragma unroll
        for (int j = 0; j < 4; j++) acc[i][j] = (f32x4)0.f;
    int srow = ln >> 2, schk = (ln & 3) * 8;
    for (int k0 = 0; k0 < K; k0 += 32) {
#pragma unroll
        for (int j = 0; j < 2; j++) {
            int r = 32 * wv + 16 * j + srow;
            async16(&As[(32 * wv + 16 * j) * 32], A + (size_t)(m0 + r) * lda + k0 + schk);
            async16(&Bs[(32 * wv + 16 * j) * 32], Bp + (size_t)(n0 + r) * ldb + k0 + schk);
        }
        __syncthreads();
        short8 af[4], bfr[4];
#pragma unroll
        for (int mi = 0; mi < 4; mi++)
            af[mi] = *(const short8*)&As[(64 * wm + 16 * mi + l15) * 32 + quad * 8];
#pragma unroll
        for (int ni = 0; ni < 4; ni++)
            bfr[ni] = *(const short8*)&Bs[(64 * wn + 16 * ni + l15) * 32 + quad * 8];
#pragma unroll
        for (int mi = 0; mi < 4; mi++)
#pragma unroll
            for (int ni = 0; ni < 4; ni++)
                acc[mi][ni] = __builtin_amdgcn_mfma_f32_16x16x32_bf16(af[mi], bfr[ni], acc[mi][ni], 0, 0, 0);
        __syncthreads();
    }
#pragma unroll
    for (int mi = 0; mi < 4; mi++) {
#pragma unroll
        for (int r = 0; r < 4; r++) {
            int row = m0 + 64 * wm + 16 * mi + quad * 4 + r;
#pragma unroll
            for (int ni = 0; ni < 4; ni++) {
                int col = n0 + 64 * wn + 16 * ni + l15;
                float v = acc[mi][ni][r];
                if (EPI == 2) v = fast_gelu(v);
                size_t idx = (size_t)row * ldc + col;
                if (OUTF) ((float*)Cv)[idx] = v;
                else      ((u16*)Cv)[idx] = f2bf(v);
            }
        }
    }
}

// ---------- bf16 GEMM 128x64 tile for MoE GEMM2 (f32 out) ----------
__global__ __launch_bounds__(256)
void gemm_moe_n64_kernel(const u16* __restrict__ A, int lda,
                         const u16* __restrict__ B, int ldb,
                         float* __restrict__ C, int ldc,
                         int K, const int* __restrict__ seg, long expStride) {
    __shared__ u16 As[128 * 32];
    __shared__ u16 Bs[64 * 32];
    int m0 = blockIdx.y * 128, n0 = blockIdx.x * 64;
    if (m0 >= seg[8]) return;
    int e = 0;
#pragma unroll
    for (int i = 1; i < 8; i++) if (m0 >= seg[i]) e = i;
    const u16* Bp = B + (long)e * expStride;
    int tid = threadIdx.x, wv = tid >> 6, ln = tid & 63;
    int quad = ln >> 4, l15 = ln & 15;
    f32x4 acc[2][4];
#pragma unroll
    for (int i = 0; i < 2; i++)
#pragma unroll
        for (int j = 0; j < 4; j++) acc[i][j] = (f32x4)0.f;
    int srow = ln >> 2, schk = (ln & 3) * 8;
    for (int k0 = 0; k0 < K; k0 += 32) {
#pragma unroll
        for (int j = 0; j < 2; j++) {
            int r = 32 * wv + 16 * j + srow;
            async16(&As[(32 * wv + 16 * j) * 32], A + (size_t)(m0 + r) * lda + k0 + schk);
        }
        {
            int r = 16 * wv + srow;
            async16(&Bs[(16 * wv) * 32], Bp + (size_t)(n0 + r) * ldb + k0 + schk);
        }
        __syncthreads();
        short8 af[2], bfr[4];
#pragma unroll
        for (int mi = 0; mi < 2; mi++)
            af[mi] = *(const short8*)&As[(32 * wv + 16 * mi + l15) * 32 + quad * 8];
#pragma unroll
        for (int ni = 0; ni < 4; ni++)
            bfr[ni] = *(const short8*)&Bs[(16 * ni + l15) * 32 + quad * 8];
#pragma unroll
        for (int mi = 0; mi < 2; mi++)
#pragma unroll
            for (int ni = 0; ni < 4; ni++)
                acc[mi][ni] = __builtin_amdgcn_mfma_f32_16x16x32_bf16(af[mi], bfr[ni], acc[mi][ni], 0, 0, 0);
        __syncthreads();
    }
#pragma unroll
    for (int mi = 0; mi < 2; mi++)
#pragma unroll
        for (int r = 0; r < 4; r++) {
            int row = m0 + 32 * wv + 16 * mi + quad * 4 + r;
#pragma unroll
            for (int ni = 0; ni < 4; ni++) {
                int col = n0 + 16 * ni + l15;
                C[(size_t)row * ldc + col] = acc[mi][ni][r];
            }
        }
}

// ---------- softmax over f32 rows of 1024; writes P hi/lo in place ----------
__global__ __launch_bounds__(256) void softmax_split_kernel(float* __restrict__ S) {
    size_t row = blockIdx.x;
    float* p = S + row * (size_t)SEQ;
    u16* ph = (u16*)p;
    u16* pl = (u16*)p + SEQ;
    int tid = threadIdx.x;
    float v[4];
#pragma unroll
    for (int i = 0; i < 4; i++) v[i] = p[tid + 256 * i];
    float m = fmaxf(fmaxf(v[0], v[1]), fmaxf(v[2], v[3]));
#pragma unroll
    for (int o = 32; o; o >>= 1) m = fmaxf(m, __shfl_down(m, o, 64));
    __shared__ float red[4], red2[4];
    if ((tid & 63) == 0) red[tid >> 6] = m;
    __syncthreads();
    m = fmaxf(fmaxf(red[0], red[1]), fmaxf(red[2], red[3]));
    float e[4], s = 0.f;
#pragma unroll
    for (int i = 0; i < 4; i++) { e[i] = expf(v[i] - m); s += e[i]; }
#pragma unroll
    for (int o = 32; o; o >>= 1) s += __shfl_down(s, o, 64);
    if ((tid & 63) == 0) red2[tid >> 6] = s;
    __syncthreads();
    s = red2[0] + red2[1] + red2[2] + red2[3];
    float inv = 1.f / s;
#pragma unroll
    for (int i = 0; i < 4; i++) {
        int c = tid + 256 * i;
        float w = e[i] * inv;
        u16 h = f2bf(w);
        ph[c] = h;
        pl[c] = f2bf(w - bf2f(h));
    }
}

// ---------- router: f32 logits, top-2, softmax weights ----------
__global__ __launch_bounds__(256) void router_kernel(const float* __restrict__ h2f,
                                                     const float* __restrict__ Wr,
                                                     int* __restrict__ topk_idx,
                                                     float* __restrict__ topk_w,
                                                     int* __restrict__ counts) {
    int t = blockIdx.x, tid = threadIdx.x;
    __shared__ float part[256 * 8];
    float l[8];
#pragma unroll
    for (int e = 0; e < 8; e++) l[e] = 0.f;
    const float* xr = h2f + (size_t)t * DIMC;
#pragma unroll
    for (int i = 0; i < 3; i++) {
        int c = tid + 256 * i;
        float xv = xr[c];
        const float* wr = Wr + (size_t)c * NEXP;
#pragma unroll
        for (int e = 0; e < 8; e++) l[e] += xv * wr[e];
    }
#pragma unroll
    for (int e = 0; e < 8; e++) part[tid * 8 + e] = l[e];
    for (int s = 128; s; s >>= 1) {
        __syncthreads();
        if (tid < s)
#pragma unroll
            for (int e = 0; e < 8; e++) part[tid * 8 + e] += part[(tid + s) * 8 + e];
    }
    __syncthreads();
    if (tid == 0) {
        float lg[8];
#pragma unroll
        for (int e = 0; e < 8; e++) lg[e] = part[e];
        int i0 = 0;
        for (int e = 1; e < 8; e++) if (lg[e] > lg[i0]) i0 = e;
        int i1 = -1;
        for (int e = 0; e < 8; e++) if (e != i0 && (i1 < 0 || lg[e] > lg[i1])) i1 = e;
        float w1 = expf(lg[i1] - lg[i0]);
        float den = 1.f + w1;
        topk_idx[2 * t] = i0; topk_idx[2 * t + 1] = i1;
        topk_w[2 * t] = 1.f / den;  topk_w[2 * t + 1] = w1 / den;
        atomicAdd(&counts[i0], 1); atomicAdd(&counts[i1], 1);
    }
}

__global__ void offsets_kernel(const int* __restrict__ counts,
                               int* __restrict__ seg, int* __restrict__ cursor) {
    if (threadIdx.x == 0 && blockIdx.x == 0) {
        int off = 0;
        for (int e = 0; e < 8; e++) {
            seg[e] = off; cursor[e] = off;
            off += ((counts[e] + 127) / 128) * 128;
        }
        seg[8] = off;
    }
}

__global__ __launch_bounds__(256) void build_perm_kernel(
    const int* __restrict__ topk_idx, const float* __restrict__ topk_w,
    int* __restrict__ cursor, int* __restrict__ perm,
    float* __restrict__ gatew, int* __restrict__ slot_of) {
    int t = blockIdx.x * 256 + threadIdx.x;
    if (t >= TOK) return;
#pragma unroll
    for (int j = 0; j < 2; j++) {
        int e = topk_idx[2 * t + j];
        int slot = atomicAdd(&cursor[e], 1);
        perm[slot] = t;
        gatew[slot] = topk_w[2 * t + j];
        slot_of[2 * t + j] = slot;
    }
}

__global__ __launch_bounds__(192) void gather_kernel(const u16* __restrict__ h2,
                                                     const int* __restrict__ perm,
                                                     u16* __restrict__ xg) {
    int slot = blockIdx.x;
    int t = perm[slot];
    const uint2* s = (const uint2*)(h2 + (size_t)t * DIMC);
    uint2* d = (uint2*)(xg + (size_t)slot * DIMC);
    d[threadIdx.x] = s[threadIdx.x];
}

__global__ __launch_bounds__(192) void combine_kernel(
    const float* __restrict__ x1, const float* __restrict__ yg,
    const float* __restrict__ gatew, const int* __restrict__ slot_of,
    float* __restrict__ out) {
    int t = blockIdx.x;
    int s0 = slot_of[2 * t], s1 = slot_of[2 * t + 1];
    float w0 = gatew[s0], w1 = gatew[s1];
    int c = threadIdx.x * 4;
    const float* xr = x1 + (size_t)t * DIMC;
    const float* y0 = yg + (size_t)s0 * DIMC;
    const float* y1 = yg + (size_t)s1 * DIMC;
    float* orow = out + (size_t)t * DIMC;
#pragma unroll
    for (int k = 0; k < 4; k++)
        orow[c + k] = xr[c + k] + w0 * y0[c + k] + w1 * y1[c + k];
}

// ---------- launcher ----------
extern "C" void kernel_launch(void* const* d_in, const int* in_sizes, int n_in,
                              void* d_out, int out_size, void* d_ws, size_t ws_size,
                              hipStream_t stream) {
    const float* x       = (const float*)d_in[0];
    const float* Wqkv    = (const float*)d_in[1];
    const float* Wproj   = (const float*)d_in[2];
    const float* Wrouter = (const float*)d_in[3];
    const float* W1      = (const float*)d_in[4];
    const float* W2      = (const float*)d_in[5];
    const float* ln1g    = (const float*)d_in[6];
    const float* ln1b    = (const float*)d_in[7];
    const float* ln2g    = (const float*)d_in[8];
    const float* ln2b    = (const float*)d_in[9];
    float* out = (float*)d_out;
    char* ws = (char*)d_ws;

    const size_t o_x1   = 0;           // 12582912 B f32 residual
    const size_t o_rout = 12582912;    // 262144 B
    const size_t P      = 12845056;    // pool base
    const size_t WS_REQ = 177995776;
    if (ws_size < WS_REQ) return;

    float* x1 = (float*)(ws + o_x1);
    // phase A (attention) inside pool:
    float* Sc    = (float*)(ws + P);                 // 50331648
    u16*   qkvh  = (u16*)(ws + P + 50331648);        // 18874368
    u16*   qkvl  = (u16*)(ws + P + 69206016);        // 18874368
    u16*   VTh   = (u16*)(ws + P + 88080384);        // 6291456
    u16*   VTl   = (u16*)(ws + P + 94371840);        // 6291456
    u16*   atth  = (u16*)(ws + P + 100663296);       // 6291456
    u16*   attl  = (u16*)(ws + P + 106954752);       // 6291456
    u16*   h1h   = (u16*)(ws + P + 113246208);       // 6291456
    u16*   h1l   = (u16*)(ws + P + 119537664);       // 6291456
    float* attf  = (float*)(ws + P + 113246208);     // 12582912, overlays h1 (dead after qkv)
    u16*   Wqh   = (u16*)(ws + P + 125829120);       // 3538944
    u16*   Wql   = (u16*)(ws + P + 129368064);       // 3538944
    u16*   Wph   = (u16*)(ws + P + 132907008);       // 1179648
    u16*   Wpl   = (u16*)(ws + P + 134086656);       // 1179648
    // phase B (MoE) overlays:
    u16*   W1T   = (u16*)(ws + P);                   // 37748736
    u16*   W2T   = (u16*)(ws + P + 37748736);        // 37748736
    u16*   h2    = (u16*)(ws + P + 75497472);        // 6291456
    float* h2f   = (float*)(ws + P + 81788928);      // 12582912
    u16*   xg    = (u16*)(ws + P + 94371840);        // 14155776
    u16*   hid   = (u16*)(ws + P + 108527616);       // 56623104
    float* yg    = (float*)(ws + P + 75497472);      // 28311552, overlays h2/h2f/xg

    int*   counts   = (int*)(ws + o_rout + 0);
    int*   seg      = (int*)(ws + o_rout + 64);
    int*   cursor   = (int*)(ws + o_rout + 128);
    int*   topk_idx = (int*)(ws + o_rout + 1024);
    float* topk_w   = (float*)(ws + o_rout + 34816);
    int*   perm     = (int*)(ws + o_rout + 68608);
    float* gatew    = (float*)(ws + o_rout + 106496);
    int*   slot_of  = (int*)(ws + o_rout + 144384);

    const long EXPSTR = (long)DIMC * FFC;

    // ===== Phase A: attention (bf16x3 split precision) =====
    transpose_split_kernel<<<dim3(NQKVC/32, DIMC/32, 1), 256, 0, stream>>>(
        Wqkv, Wqh, Wql, NQKVC, DIMC, 0, 0);
    transpose_split_kernel<<<dim3(DIMC/32, DIMC/32, 1), 256, 0, stream>>>(
        Wproj, Wph, Wpl, DIMC, DIMC, 0, 0);
    ln_split_kernel<<<TOK, 256, 0, stream>>>(x, ln1g, ln1b, h1h, h1l);
    // qkv = h1 @ Wqkv  -> hi/lo split out
    gemm3_kernel<0,2><<<dim3(NQKVC/128, TOK/128, 1), 256, 0, stream>>>(
        h1h, h1l, DIMC, 0, Wqh, Wql, DIMC, 0,
        qkvh, qkvl, NQKVC, 0, TOK, NQKVC, DIMC, 1.f, nullptr);
    // h1 dead now -> attf overlays it; zero for PV atomics
    (void)hipMemsetAsync(attf, 0, 12582912, stream);
    // VT[b,h][d][t] = V[b,h][t][d]  (hi and lo)
    transpose_b2b_kernel<<<dim3(HDIM/32, SEQ/32, NBATCH*NHEAD), 256, 0, stream>>>(
        qkvh + 2 * DIMC, VTh, NQKVC, SEQ, (long)SEQ * NQKVC, NHEAD, (long)HDIM, (long)HDIM * SEQ);
    transpose_b2b_kernel<<<dim3(HDIM/32, SEQ/32, NBATCH*NHEAD), 256, 0, stream>>>(
        qkvl + 2 * DIMC, VTl, NQKVC, SEQ, (long)SEQ * NQKVC, NHEAD, (long)HDIM, (long)HDIM * SEQ);
    for (int b = 0; b < NBATCH; b++) {
        const u16* qbh = qkvh + (size_t)b * SEQ * NQKVC;
        const u16* qbl = qkvl + (size_t)b * SEQ * NQKVC;
        // Sc[h][q][k] = 0.125 * Q.K^T  (f32 out)
        gemm3_kernel<0,1><<<dim3(SEQ/128, SEQ/128, NHEAD), 256, 0, stream>>>(
            qbh, qbl, NQKVC, (long)HDIM,
            qbh + DIMC, qbl + DIMC, NQKVC, (long)HDIM,
            Sc, nullptr, SEQ, (long)SEQ * SEQ,
            SEQ, SEQ, HDIM, 0.125f, nullptr);
        softmax_split_kernel<<<NHEAD * SEQ, 256, 0, stream>>>(Sc);
        // attf[b] += P.V   (split-K 4, f32 atomics)
        gemm3_pv_kernel<<<dim3(4, SEQ/64, NHEAD), 256, 0, stream>>>(
            (const u16*)Sc,
            VTh + (size_t)b * NHEAD * HDIM * SEQ, VTl + (size_t)b * NHEAD * HDIM * SEQ,
            attf, b);
    }
    // attf -> hi/lo for proj
    split_hl_kernel<<<(TOK * DIMC) / 1024, 256, 0, stream>>>(attf, atth, attl);
    // x1 = x + attno @ Wproj  (f32 out)
    gemm3_kernel<3,1><<<dim3(DIMC/128, TOK/128, 1), 256, 0, stream>>>(
        atth, attl, DIMC, 0, Wph, Wpl, DIMC, 0,
        x1, nullptr, DIMC, 0, TOK, DIMC, DIMC, 1.f, x);

    // ===== Phase B: MoE (overlays phase-A pool) =====
    transpose_f2b_kernel<<<dim3(FFC/32, DIMC/32, NEXP), 256, 0, stream>>>(
        W1, W1T, FFC, DIMC, EXPSTR, EXPSTR);
    transpose_f2b_kernel<<<dim3(DIMC/32, FFC/32, NEXP), 256, 0, stream>>>(
        W2, W2T, DIMC, FFC, EXPSTR, EXPSTR);
    ln_bf_kernel<<<TOK, 256, 0, stream>>>(x1, ln2g, ln2b, h2, h2f);
    (void)hipMemsetAsync(ws + o_rout, 0, 262144, stream);
    router_kernel<<<TOK, 256, 0, stream>>>(h2f, Wrouter, topk_idx, topk_w, counts);
    offsets_kernel<<<1, 64, 0, stream>>>(counts, seg, cursor);
    build_perm_kernel<<<16, 256, 0, stream>>>(topk_idx, topk_w, cursor, perm, gatew, slot_of);
    gather_kernel<<<SLOTS, 192, 0, stream>>>(h2, perm, xg);
    // hid = gelu(xg @ W1[e])  bf16 out
    gemm_moe_kernel<2,0><<<dim3(FFC/128, SLOTS/128, 1), 256, 0, stream>>>(
        xg, DIMC, W1T, DIMC, hid, FFC, FFC, DIMC, seg, EXPSTR);
    // yg = hid @ W2[e]  f32 out, 128x64 tiles for 2x grid parallelism
    gemm_moe_n64_kernel<<<dim3(DIMC/64, SLOTS/128, 1), 256, 0, stream>>>(
        hid, FFC, W2T, FFC, yg, DIMC, FFC, seg, EXPSTR);
    combine_kernel<<<TOK, 192, 0, stream>>>(x1, yg, gatew, slot_of, out);

    (void)in_sizes; (void)n_in; (void)out_size;
}

// Round 5
// 827.186 us; speedup vs baseline: 1.2313x; 1.0745x over previous
//
#include <hip/hip_runtime.h>
#include <math.h>

typedef unsigned short u16;
typedef __attribute__((ext_vector_type(8))) short short8;
typedef __attribute__((ext_vector_type(4))) float f32x4;

#define DIMC   768
#define TOK    4096
#define NQKVC  2304
#define FFC    3072
#define NEXP   8
#define NHEAD  12
#define HDIM   64
#define SEQ    1024
#define NBATCH 4
#define SLOTS  9216   // 8192 + per-expert 128-pad slack (max 9208)

// ---------- bf16 helpers ----------
__device__ __forceinline__ float bf2f(u16 v) {
    unsigned int u = ((unsigned int)v) << 16;
    float f; __builtin_memcpy(&f, &u, 4); return f;
}
__device__ __forceinline__ u16 f2bf(float f) {
    unsigned int u; __builtin_memcpy(&u, &f, 4);
    u = (u + 0x7fffu + ((u >> 16) & 1u)) >> 16;
    return (u16)u;
}

// fast gelu-exact: erf via A&S 7.1.26 (|eps|<=1.5e-7)
__device__ __forceinline__ float fast_gelu(float v) {
    float x = fabsf(v) * 0.70710678118654752f;
    float t = __builtin_amdgcn_rcpf(1.f + 0.3275911f * x);
    float y = t * (0.254829592f + t * (-0.284496736f + t * (1.421413741f +
              t * (-1.453152027f + t * 1.061405429f))));
    float er = 1.f - y * __expf(-x * x);
    er = (v < 0.f) ? -er : er;
    return 0.5f * v * (1.f + er);
}

// async global->LDS, 16B per lane. lds base wave-uniform; HW adds lane*16.
__device__ __forceinline__ void async16(u16* lds, const u16* gp) {
    __builtin_amdgcn_global_load_lds(
        (const __attribute__((address_space(1))) unsigned int*)gp,
        (__attribute__((address_space(3))) unsigned int*)lds, 16, 0, 0);
}

// ---------- LayerNorm: f32 in -> hi/lo bf16 split out ----------
__global__ __launch_bounds__(256) void ln_split_kernel(const float* __restrict__ x,
                                                       const float* __restrict__ g,
                                                       const float* __restrict__ b,
                                                       u16* __restrict__ yh,
                                                       u16* __restrict__ yl) {
    int row = blockIdx.x, tid = threadIdx.x;
    const float* xr = x + (size_t)row * DIMC;
    float v[3];
#pragma unroll
    for (int i = 0; i < 3; i++) v[i] = xr[tid + 256 * i];
    float s = v[0] + v[1] + v[2];
    float q = v[0]*v[0] + v[1]*v[1] + v[2]*v[2];
#pragma unroll
    for (int o = 32; o; o >>= 1) { s += __shfl_down(s, o, 64); q += __shfl_down(q, o, 64); }
    __shared__ float rs[4], rq[4];
    if ((tid & 63) == 0) { rs[tid >> 6] = s; rq[tid >> 6] = q; }
    __syncthreads();
    s = rs[0] + rs[1] + rs[2] + rs[3];
    q = rq[0] + rq[1] + rq[2] + rq[3];
    float mean = s * (1.f / DIMC);
    float var  = q * (1.f / DIMC) - mean * mean;
    float rstd = rsqrtf(var + 1e-5f);
#pragma unroll
    for (int i = 0; i < 3; i++) {
        int c = tid + 256 * i;
        float o = (v[i] - mean) * rstd * g[c] + b[c];
        u16 h = f2bf(o);
        yh[(size_t)row * DIMC + c] = h;
        yl[(size_t)row * DIMC + c] = f2bf(o - bf2f(h));
    }
}

// ---------- LayerNorm: f32 in -> bf16 out + f32 out (for MoE/router) ----------
__global__ __launch_bounds__(256) void ln_bf_kernel(const float* __restrict__ x,
                                                    const float* __restrict__ g,
                                                    const float* __restrict__ b,
                                                    u16* __restrict__ yb,
                                                    float* __restrict__ yf) {
    int row = blockIdx.x, tid = threadIdx.x;
    const float* xr = x + (size_t)row * DIMC;
    float v[3];
#pragma unroll
    for (int i = 0; i < 3; i++) v[i] = xr[tid + 256 * i];
    float s = v[0] + v[1] + v[2];
    float q = v[0]*v[0] + v[1]*v[1] + v[2]*v[2];
#pragma unroll
    for (int o = 32; o; o >>= 1) { s += __shfl_down(s, o, 64); q += __shfl_down(q, o, 64); }
    __shared__ float rs[4], rq[4];
    if ((tid & 63) == 0) { rs[tid >> 6] = s; rq[tid >> 6] = q; }
    __syncthreads();
    s = rs[0] + rs[1] + rs[2] + rs[3];
    q = rq[0] + rq[1] + rq[2] + rq[3];
    float mean = s * (1.f / DIMC);
    float var  = q * (1.f / DIMC) - mean * mean;
    float rstd = rsqrtf(var + 1e-5f);
#pragma unroll
    for (int i = 0; i < 3; i++) {
        int c = tid + 256 * i;
        float o = (v[i] - mean) * rstd * g[c] + b[c];
        yb[(size_t)row * DIMC + c] = f2bf(o);
        yf[(size_t)row * DIMC + c] = o;
    }
}

// ---------- f32 src -> hi/lo bf16 split (elementwise) ----------
__global__ __launch_bounds__(256) void split_hl_kernel(const float* __restrict__ src,
                                                       u16* __restrict__ dh,
                                                       u16* __restrict__ dl) {
    size_t i = ((size_t)blockIdx.x * 256 + threadIdx.x) * 4;
#pragma unroll
    for (int k = 0; k < 4; k++) {
        float v = src[i + k];
        u16 h = f2bf(v);
        dh[i + k] = h;
        dl[i + k] = f2bf(v - bf2f(h));
    }
}

// ---------- transpose f32 src -> hi/lo bf16 dsts ----------
__global__ __launch_bounds__(256) void transpose_split_kernel(
    const float* __restrict__ src, u16* __restrict__ dh, u16* __restrict__ dl,
    int s_rs, int d_rs, long s_bs, long d_bs) {
    __shared__ u16 th[32][33], tl[32][33];
    int z = blockIdx.z;
    const float* sb = src + (long)z * s_bs;
    int r0 = blockIdx.y * 32, c0 = blockIdx.x * 32;
    int tx = threadIdx.x & 31, ty = threadIdx.x >> 5;
#pragma unroll
    for (int i = 0; i < 4; i++) {
        float v = sb[(size_t)(r0 + ty + 8 * i) * s_rs + c0 + tx];
        u16 h = f2bf(v);
        th[ty + 8 * i][tx] = h;
        tl[ty + 8 * i][tx] = f2bf(v - bf2f(h));
    }
    __syncthreads();
#pragma unroll
    for (int i = 0; i < 4; i++) {
        size_t o = (long)z * d_bs + (size_t)(c0 + ty + 8 * i) * d_rs + r0 + tx;
        dh[o] = th[tx][ty + 8 * i];
        dl[o] = tl[tx][ty + 8 * i];
    }
}

// ---------- transpose f32 src -> hi-only bf16 dst (MoE weights) ----------
__global__ __launch_bounds__(256) void transpose_f2b_kernel(
    const float* __restrict__ src, u16* __restrict__ dst,
    int s_rs, int d_rs, long s_bs, long d_bs) {
    __shared__ u16 tile[32][33];
    int z = blockIdx.z;
    const float* sb = src + (long)z * s_bs;
    int r0 = blockIdx.y * 32, c0 = blockIdx.x * 32;
    int tx = threadIdx.x & 31, ty = threadIdx.x >> 5;
#pragma unroll
    for (int i = 0; i < 4; i++)
        tile[ty + 8 * i][tx] = f2bf(sb[(size_t)(r0 + ty + 8 * i) * s_rs + c0 + tx]);
    __syncthreads();
#pragma unroll
    for (int i = 0; i < 4; i++)
        dst[(long)z * d_bs + (size_t)(c0 + ty + 8 * i) * d_rs + r0 + tx] = tile[tx][ty + 8 * i];
}

// ---------- bf16 batched transpose (V -> VT, run for hi and lo) ----------
__global__ __launch_bounds__(256) void transpose_b2b_kernel(
    const u16* __restrict__ src, u16* __restrict__ dst,
    int s_rs, int d_rs, long s_bs1, int s_n1, long s_bs2, long d_bs) {
    __shared__ u16 tile[32][33];
    int z = blockIdx.z;
    const u16* sb = src + (long)(z / s_n1) * s_bs1 + (long)(z % s_n1) * s_bs2;
    u16* db = dst + (long)z * d_bs;
    int r0 = blockIdx.y * 32, c0 = blockIdx.x * 32;
    int tx = threadIdx.x & 31, ty = threadIdx.x >> 5;
#pragma unroll
    for (int i = 0; i < 4; i++)
        tile[ty + 8 * i][tx] = sb[(size_t)(r0 + ty + 8 * i) * s_rs + c0 + tx];
    __syncthreads();
#pragma unroll
    for (int i = 0; i < 4; i++)
        db[(size_t)(c0 + ty + 8 * i) * d_rs + r0 + tx] = tile[tx][ty + 8 * i];
}

// ---------- split-precision GEMM: C = alpha*(A.Bt), A=Ah+Al, B=Bh+Bl ----------
// 3-term: ah.bh + ah.bl + al.bh  (rel err ~2^-17)
// EPI: 0 none ; 3 add f32 residual R.  OUT: 1 f32 store ; 2 hi/lo bf16 split store
template<int EPI, int OUT>
__global__ __launch_bounds__(256)
void gemm3_kernel(const u16* __restrict__ Ah, const u16* __restrict__ Al, int lda, long aBS,
                  const u16* __restrict__ Bh, const u16* __restrict__ Bl, int ldb, long bBS,
                  void* __restrict__ C0, void* __restrict__ C1, int ldc, long cBS,
                  int M, int N, int K, float alpha, const float* __restrict__ R) {
    __shared__ u16 Ash[128 * 32], Asl[128 * 32], Bsh[128 * 32], Bsl[128 * 32];
    int bm = blockIdx.y, bn = blockIdx.x, bz = blockIdx.z;
    int m0 = bm * 128, n0 = bn * 128;
    const u16* Ahb = Ah + (long)bz * aBS;
    const u16* Alb = Al + (long)bz * aBS;
    const u16* Bhb = Bh + (long)bz * bBS;
    const u16* Blb = Bl + (long)bz * bBS;
    int tid = threadIdx.x, wv = tid >> 6, ln = tid & 63;
    int quad = ln >> 4, l15 = ln & 15;
    int wm = wv & 1, wn = wv >> 1;
    f32x4 acc[4][4];
#pragma unroll
    for (int i = 0; i < 4; i++)
#pragma unroll
        for (int j = 0; j < 4; j++) acc[i][j] = (f32x4)0.f;
    int srow = ln >> 2, schk = (ln & 3) * 8;

    for (int k0 = 0; k0 < K; k0 += 32) {
#pragma unroll
        for (int j = 0; j < 2; j++) {
            int r = 32 * wv + 16 * j + srow;
            size_t ao = (size_t)(m0 + r) * lda + k0 + schk;
            async16(&Ash[(32 * wv + 16 * j) * 32], Ahb + ao);
            async16(&Asl[(32 * wv + 16 * j) * 32], Alb + ao);
            size_t bo = (size_t)(n0 + r) * ldb + k0 + schk;
            async16(&Bsh[(32 * wv + 16 * j) * 32], Bhb + bo);
            async16(&Bsl[(32 * wv + 16 * j) * 32], Blb + bo);
        }
        __syncthreads();
        short8 ah[4], al4[4], bh[4], bl4[4];
#pragma unroll
        for (int mi = 0; mi < 4; mi++) {
            int off = (64 * wm + 16 * mi + l15) * 32 + quad * 8;
            ah[mi]  = *(const short8*)&Ash[off];
            al4[mi] = *(const short8*)&Asl[off];
        }
#pragma unroll
        for (int ni = 0; ni < 4; ni++) {
            int off = (64 * wn + 16 * ni + l15) * 32 + quad * 8;
            bh[ni]  = *(const short8*)&Bsh[off];
            bl4[ni] = *(const short8*)&Bsl[off];
        }
#pragma unroll
        for (int mi = 0; mi < 4; mi++)
#pragma unroll
            for (int ni = 0; ni < 4; ni++) {
                acc[mi][ni] = __builtin_amdgcn_mfma_f32_16x16x32_bf16(ah[mi],  bh[ni],  acc[mi][ni], 0, 0, 0);
                acc[mi][ni] = __builtin_amdgcn_mfma_f32_16x16x32_bf16(ah[mi],  bl4[ni], acc[mi][ni], 0, 0, 0);
                acc[mi][ni] = __builtin_amdgcn_mfma_f32_16x16x32_bf16(al4[mi], bh[ni],  acc[mi][ni], 0, 0, 0);
            }
        __syncthreads();
    }
#pragma unroll
    for (int mi = 0; mi < 4; mi++) {
#pragma unroll
        for (int r = 0; r < 4; r++) {
            int row = m0 + 64 * wm + 16 * mi + quad * 4 + r;
#pragma unroll
            for (int ni = 0; ni < 4; ni++) {
                int col = n0 + 64 * wn + 16 * ni + l15;
                size_t idx = (long)bz * cBS + (size_t)row * ldc + col;
                float v = acc[mi][ni][r] * alpha;
                if (EPI == 3) v += R[idx];
                if (OUT == 1) ((float*)C0)[idx] = v;
                else {
                    u16 h = f2bf(v);
                    ((u16*)C0)[idx] = h;
                    ((u16*)C1)[idx] = f2bf(v - bf2f(h));
                }
            }
        }
    }
}

// ---------- softmax stats: per f32 row of 1024, write {max, 1/sum} ----------
__global__ __launch_bounds__(256) void softmax_stats_kernel(const float* __restrict__ S,
                                                            float* __restrict__ stats) {
    size_t row = blockIdx.x;
    const float* p = S + row * (size_t)SEQ;
    int tid = threadIdx.x;
    float v[4];
#pragma unroll
    for (int i = 0; i < 4; i++) v[i] = p[tid + 256 * i];
    float m = fmaxf(fmaxf(v[0], v[1]), fmaxf(v[2], v[3]));
#pragma unroll
    for (int o = 32; o; o >>= 1) m = fmaxf(m, __shfl_down(m, o, 64));
    __shared__ float red[4], red2[4];
    if ((tid & 63) == 0) red[tid >> 6] = m;
    __syncthreads();
    m = fmaxf(fmaxf(red[0], red[1]), fmaxf(red[2], red[3]));
    float s = 0.f;
#pragma unroll
    for (int i = 0; i < 4; i++) s += __expf(v[i] - m);
#pragma unroll
    for (int o = 32; o; o >>= 1) s += __shfl_down(s, o, 64);
    if ((tid & 63) == 0) red2[tid >> 6] = s;
    __syncthreads();
    if (tid == 0) {
        s = red2[0] + red2[1] + red2[2] + red2[3];
        stats[row * 2]     = m;
        stats[row * 2 + 1] = 1.f / s;
    }
}

// ---------- PV fused: exp+split in staging, 64x64 tile, split-K, atomic f32 ----------
// grid (4, SEQ/64, NHEAD). O[q][h*64+d] += softmax(S)[h,q,:].V[h,:,d]
__global__ __launch_bounds__(256)
void pv_fused_kernel(const float* __restrict__ Sc, const float* __restrict__ stats,
                     const u16* __restrict__ VTh_, const u16* __restrict__ VTl_,
                     float* __restrict__ attf, int b) {
    __shared__ u16 Psh[64 * 32], Psl[64 * 32], Bsh[64 * 32], Bsl[64 * 32];
    __shared__ float sm[64], sl[64];
    int kz = blockIdx.x, qt = blockIdx.y, h = blockIdx.z;
    int tid = threadIdx.x, wv = tid >> 6, ln = tid & 63;
    int quad = ln >> 4, l15 = ln & 15;
    int m0 = qt * 64;
    const float* Sh = Sc + (size_t)h * SEQ * SEQ;
    const u16* Bh = VTh_ + (size_t)h * HDIM * SEQ;
    const u16* Bl = VTl_ + (size_t)h * HDIM * SEQ;
    if (tid < 64) {
        sm[tid] = stats[(h * SEQ + m0 + tid) * 2];
        sl[tid] = stats[(h * SEQ + m0 + tid) * 2 + 1];
    }
    f32x4 acc[4];
#pragma unroll
    for (int i = 0; i < 4; i++) acc[i] = (f32x4)0.f;
    int prow = tid >> 2;          // 0..63
    int pk   = (tid & 3) * 8;     // 0,8,16,24
    int srow = ln >> 2, schk = (ln & 3) * 8;
    int kbase = kz * (SEQ / 4);
    __syncthreads();   // sm/sl visible
    for (int k0 = kbase; k0 < kbase + SEQ / 4; k0 += 32) {
        // B staging (async16)
        {
            int r = 16 * wv + srow;
            async16(&Bsh[(16 * wv) * 32], Bh + (size_t)r * SEQ + k0 + schk);
            async16(&Bsl[(16 * wv) * 32], Bl + (size_t)r * SEQ + k0 + schk);
        }
        // P staging: read raw scores, exp, scale, split (registers only)
        const float* sp = Sh + (size_t)(m0 + prow) * SEQ + k0 + pk;
        float4 s0 = *(const float4*)sp;
        float4 s1 = *(const float4*)(sp + 4);
        float mr = sm[prow], lr = sl[prow];
        float pv[8] = { s0.x, s0.y, s0.z, s0.w, s1.x, s1.y, s1.z, s1.w };
        union { u16 u[8]; uint4 v; } ph, pl;
#pragma unroll
        for (int j = 0; j < 8; j++) {
            float p = __expf(pv[j] - mr) * lr;
            u16 hh = f2bf(p);
            ph.u[j] = hh;
            pl.u[j] = f2bf(p - bf2f(hh));
        }
        *(uint4*)&Psh[prow * 32 + pk] = ph.v;
        *(uint4*)&Psl[prow * 32 + pk] = pl.v;
        __syncthreads();   // ds_writes visible + async16 drained
        short8 a_h = *(const short8*)&Psh[(16 * wv + l15) * 32 + quad * 8];
        short8 a_l = *(const short8*)&Psl[(16 * wv + l15) * 32 + quad * 8];
#pragma unroll
        for (int ni = 0; ni < 4; ni++) {
            short8 b_h = *(const short8*)&Bsh[(16 * ni + l15) * 32 + quad * 8];
            short8 b_l = *(const short8*)&Bsl[(16 * ni + l15) * 32 + quad * 8];
            acc[ni] = __builtin_amdgcn_mfma_f32_16x16x32_bf16(a_h, b_h, acc[ni], 0, 0, 0);
            acc[ni] = __builtin_amdgcn_mfma_f32_16x16x32_bf16(a_h, b_l, acc[ni], 0, 0, 0);
            acc[ni] = __builtin_amdgcn_mfma_f32_16x16x32_bf16(a_l, b_h, acc[ni], 0, 0, 0);
        }
        __syncthreads();   // protect LDS before next stage
    }
#pragma unroll
    for (int ni = 0; ni < 4; ni++)
#pragma unroll
        for (int r = 0; r < 4; r++) {
            int q = m0 + 16 * wv + quad * 4 + r;
            int d = h * HDIM + 16 * ni + l15;
            atomicAdd(&attf[((size_t)b * SEQ + q) * DIMC + d], acc[ni][r]);
        }
}

// ---------- MoE GEMM1: 128x128, BK=64, XCD swizzle, gelu, bf16 out ----------
// grid 1D = 1728 = 8 xcd * (9 m * 24 n)
__global__ __launch_bounds__(256)
void gemm1_kernel(const u16* __restrict__ A, const u16* __restrict__ B,
                  u16* __restrict__ C, const int* __restrict__ seg) {
    __shared__ u16 As[2 * 128 * 32];   // [kh][row][32]
    __shared__ u16 Bs[2 * 128 * 32];
    int i = blockIdx.x;
    int mt = (i & 7) * 9 + ((i >> 3) % 9);
    int nt = (i >> 3) / 9;
    int m0 = mt * 128, n0 = nt * 128;
    if (m0 >= seg[8]) return;
    int e = 0;
#pragma unroll
    for (int j = 1; j < 8; j++) if (m0 >= seg[j]) e = j;
    const u16* Bp = B + (long)e * DIMC * FFC;
    int tid = threadIdx.x, wv = tid >> 6, ln = tid & 63;
    int quad = ln >> 4, l15 = ln & 15;
    int wm = wv & 1, wn = wv >> 1;
    f32x4 acc[4][4];
#pragma unroll
    for (int a = 0; a < 4; a++)
#pragma unroll
        for (int c = 0; c < 4; c++) acc[a][c] = (f32x4)0.f;
    int srow = ln >> 2, schk = (ln & 3) * 8;
    for (int k0 = 0; k0 < DIMC; k0 += 64) {
#pragma unroll
        for (int j = 0; j < 2; j++) {
            int r = 32 * wv + 16 * j + srow;
#pragma unroll
            for (int kh = 0; kh < 2; kh++) {
                async16(&As[kh * 4096 + (32 * wv + 16 * j) * 32],
                        A + (size_t)(m0 + r) * DIMC + k0 + kh * 32 + schk);
                async16(&Bs[kh * 4096 + (32 * wv + 16 * j) * 32],
                        Bp + (size_t)(n0 + r) * DIMC + k0 + kh * 32 + schk);
            }
        }
        __syncthreads();
#pragma unroll
        for (int kh = 0; kh < 2; kh++) {
            short8 af[4], bfr[4];
#pragma unroll
            for (int mi = 0; mi < 4; mi++)
                af[mi] = *(const short8*)&As[kh * 4096 + (64 * wm + 16 * mi + l15) * 32 + quad * 8];
#pragma unroll
            for (int ni = 0; ni < 4; ni++)
                bfr[ni] = *(const short8*)&Bs[kh * 4096 + (64 * wn + 16 * ni + l15) * 32 + quad * 8];
#pragma unroll
            for (int mi = 0; mi < 4; mi++)
#pragma unroll
                for (int ni = 0; ni < 4; ni++)
                    acc[mi][ni] = __builtin_amdgcn_mfma_f32_16x16x32_bf16(af[mi], bfr[ni], acc[mi][ni], 0, 0, 0);
        }
        __syncthreads();
    }
#pragma unroll
    for (int mi = 0; mi < 4; mi++)
#pragma unroll
        for (int r = 0; r < 4; r++) {
            int row = m0 + 64 * wm + 16 * mi + quad * 4 + r;
#pragma unroll
            for (int ni = 0; ni < 4; ni++) {
                int col = n0 + 64 * wn + 16 * ni + l15;
                C[(size_t)row * FFC + col] = f2bf(fast_gelu(acc[mi][ni][r]));
            }
        }
}

// ---------- MoE GEMM2: 128x64, BK=64, XCD swizzle, f32 out ----------
// grid 1D = 864 = 8 xcd * (9 m * 12 n)
__global__ __launch_bounds__(256)
void gemm2_kernel(const u16* __restrict__ A, const u16* __restrict__ B,
                  float* __restrict__ C, const int* __restrict__ seg) {
    __shared__ u16 As[2 * 128 * 32];   // 16KB
    __shared__ u16 Bs[2 * 64 * 32];    // 8KB
    int i = blockIdx.x;
    int mt = (i & 7) * 9 + ((i >> 3) % 9);
    int nt = (i >> 3) / 9;
    int m0 = mt * 128, n0 = nt * 64;
    if (m0 >= seg[8]) return;
    int e = 0;
#pragma unroll
    for (int j = 1; j < 8; j++) if (m0 >= seg[j]) e = j;
    const u16* Bp = B + (long)e * DIMC * FFC;
    int tid = threadIdx.x, wv = tid >> 6, ln = tid & 63;
    int quad = ln >> 4, l15 = ln & 15;
    f32x4 acc[2][4];
#pragma unroll
    for (int a = 0; a < 2; a++)
#pragma unroll
        for (int c = 0; c < 4; c++) acc[a][c] = (f32x4)0.f;
    int srow = ln >> 2, schk = (ln & 3) * 8;
    for (int k0 = 0; k0 < FFC; k0 += 64) {
#pragma unroll
        for (int j = 0; j < 2; j++) {
            int r = 32 * wv + 16 * j + srow;
#pragma unroll
            for (int kh = 0; kh < 2; kh++)
                async16(&As[kh * 4096 + (32 * wv + 16 * j) * 32],
                        A + (size_t)(m0 + r) * FFC + k0 + kh * 32 + schk);
        }
        {
            int r = 16 * wv + srow;
#pragma unroll
            for (int kh = 0; kh < 2; kh++)
                async16(&Bs[kh * 2048 + (16 * wv) * 32],
                        Bp + (size_t)(n0 + r) * FFC + k0 + kh * 32 + schk);
        }
        __syncthreads();
#pragma unroll
        for (int kh = 0; kh < 2; kh++) {
            short8 af[2], bfr[4];
#pragma unroll
            for (int mi = 0; mi < 2; mi++)
                af[mi] = *(const short8*)&As[kh * 4096 + (32 * wv + 16 * mi + l15) * 32 + quad * 8];
#pragma unroll
            for (int ni = 0; ni < 4; ni++)
                bfr[ni] = *(const short8*)&Bs[kh * 2048 + (16 * ni + l15) * 32 + quad * 8];
#pragma unroll
            for (int mi = 0; mi < 2; mi++)
#pragma unroll
                for (int ni = 0; ni < 4; ni++)
                    acc[mi][ni] = __builtin_amdgcn_mfma_f32_16x16x32_bf16(af[mi], bfr[ni], acc[mi][ni], 0, 0, 0);
        }
        __syncthreads();
    }
#pragma unroll
    for (int mi = 0; mi < 2; mi++)
#pragma unroll
        for (int r = 0; r < 4; r++) {
            int row = m0 + 32 * wv + 16 * mi + quad * 4 + r;
#pragma unroll
            for (int ni = 0; ni < 4; ni++) {
                int col = n0 + 16 * ni + l15;
                C[(size_t)row * DIMC + col] = acc[mi][ni][r];
            }
        }
}

// ---------- router: f32 logits, top-2, softmax weights ----------
__global__ __launch_bounds__(256) void router_kernel(const float* __restrict__ h2f,
                                                     const float* __restrict__ Wr,
                                                     int* __restrict__ topk_idx,
                                                     float* __restrict__ topk_w,
                                                     int* __restrict__ counts) {
    int t = blockIdx.x, tid = threadIdx.x;
    __shared__ float part[256 * 8];
    float l[8];
#pragma unroll
    for (int e = 0; e < 8; e++) l[e] = 0.f;
    const float* xr = h2f + (size_t)t * DIMC;
#pragma unroll
    for (int i = 0; i < 3; i++) {
        int c = tid + 256 * i;
        float xv = xr[c];
        const float* wr = Wr + (size_t)c * NEXP;
#pragma unroll
        for (int e = 0; e < 8; e++) l[e] += xv * wr[e];
    }
#pragma unroll
    for (int e = 0; e < 8; e++) part[tid * 8 + e] = l[e];
    for (int s = 128; s; s >>= 1) {
        __syncthreads();
        if (tid < s)
#pragma unroll
            for (int e = 0; e < 8; e++) part[tid * 8 + e] += part[(tid + s) * 8 + e];
    }
    __syncthreads();
    if (tid == 0) {
        float lg[8];
#pragma unroll
        for (int e = 0; e < 8; e++) lg[e] = part[e];
        int i0 = 0;
        for (int e = 1; e < 8; e++) if (lg[e] > lg[i0]) i0 = e;
        int i1 = -1;
        for (int e = 0; e < 8; e++) if (e != i0 && (i1 < 0 || lg[e] > lg[i1])) i1 = e;
        float w1 = expf(lg[i1] - lg[i0]);
        float den = 1.f + w1;
        topk_idx[2 * t] = i0; topk_idx[2 * t + 1] = i1;
        topk_w[2 * t] = 1.f / den;  topk_w[2 * t + 1] = w1 / den;
        atomicAdd(&counts[i0], 1); atomicAdd(&counts[i1], 1);
    }
}

__global__ void offsets_kernel(const int* __restrict__ counts,
                               int* __restrict__ seg, int* __restrict__ cursor) {
    if (threadIdx.x == 0 && blockIdx.x == 0) {
        int off = 0;
        for (int e = 0; e < 8; e++) {
            seg[e] = off; cursor[e] = off;
            off += ((counts[e] + 127) / 128) * 128;
        }
        seg[8] = off;
    }
}

__global__ __launch_bounds__(256) void build_perm_kernel(
    const int* __restrict__ topk_idx, const float* __restrict__ topk_w,
    int* __restrict__ cursor, int* __restrict__ perm,
    float* __restrict__ gatew, int* __restrict__ slot_of) {
    int t = blockIdx.x * 256 + threadIdx.x;
    if (t >= TOK) return;
#pragma unroll
    for (int j = 0; j < 2; j++) {
        int e = topk_idx[2 * t + j];
        int slot = atomicAdd(&cursor[e], 1);
        perm[slot] = t;
        gatew[slot] = topk_w[2 * t + j];
        slot_of[2 * t + j] = slot;
    }
}

__global__ __launch_bounds__(192) void gather_kernel(const u16* __restrict__ h2,
                                                     const int* __restrict__ perm,
                                                     u16* __restrict__ xg) {
    int slot = blockIdx.x;
    int t = perm[slot];
    const uint2* s = (const uint2*)(h2 + (size_t)t * DIMC);
    uint2* d = (uint2*)(xg + (size_t)slot * DIMC);
    d[threadIdx.x] = s[threadIdx.x];
}

__global__ __launch_bounds__(192) void combine_kernel(
    const float* __restrict__ x1, const float* __restrict__ yg,
    const float* __restrict__ gatew, const int* __restrict__ slot_of,
    float* __restrict__ out) {
    int t = blockIdx.x;
    int s0 = slot_of[2 * t], s1 = slot_of[2 * t + 1];
    float w0 = gatew[s0], w1 = gatew[s1];
    int c = threadIdx.x * 4;
    const float* xr = x1 + (size_t)t * DIMC;
    const float* y0 = yg + (size_t)s0 * DIMC;
    const float* y1 = yg + (size_t)s1 * DIMC;
    float* orow = out + (size_t)t * DIMC;
#pragma unroll
    for (int k = 0; k < 4; k++)
        orow[c + k] = xr[c + k] + w0 * y0[c + k] + w1 * y1[c + k];
}

// ---------- launcher ----------
extern "C" void kernel_launch(void* const* d_in, const int* in_sizes, int n_in,
                              void* d_out, int out_size, void* d_ws, size_t ws_size,
                              hipStream_t stream) {
    const float* x       = (const float*)d_in[0];
    const float* Wqkv    = (const float*)d_in[1];
    const float* Wproj   = (const float*)d_in[2];
    const float* Wrouter = (const float*)d_in[3];
    const float* W1      = (const float*)d_in[4];
    const float* W2      = (const float*)d_in[5];
    const float* ln1g    = (const float*)d_in[6];
    const float* ln1b    = (const float*)d_in[7];
    const float* ln2g    = (const float*)d_in[8];
    const float* ln2b    = (const float*)d_in[9];
    float* out = (float*)d_out;
    char* ws = (char*)d_ws;

    const size_t o_x1   = 0;           // 12582912 B f32 residual
    const size_t o_rout = 12582912;    // 262144 B
    const size_t P      = 12845056;    // pool base
    const size_t WS_REQ = 177995776;
    if (ws_size < WS_REQ) return;

    float* x1 = (float*)(ws + o_x1);
    // phase A (attention) inside pool:
    float* Sc    = (float*)(ws + P);                 // 50331648 (raw f32 scores per batch)
    u16*   qkvh  = (u16*)(ws + P + 50331648);        // 18874368
    u16*   qkvl  = (u16*)(ws + P + 69206016);        // 18874368
    u16*   VTh   = (u16*)(ws + P + 88080384);        // 6291456
    u16*   VTl   = (u16*)(ws + P + 94371840);        // 6291456
    u16*   atth  = (u16*)(ws + P + 100663296);       // 6291456
    u16*   attl  = (u16*)(ws + P + 106954752);       // 6291456
    u16*   h1h   = (u16*)(ws + P + 113246208);       // 6291456
    u16*   h1l   = (u16*)(ws + P + 119537664);       // 6291456
    float* attf  = (float*)(ws + P + 113246208);     // 12582912, overlays h1 (dead after qkv)
    u16*   Wqh   = (u16*)(ws + P + 125829120);       // 3538944
    u16*   Wql   = (u16*)(ws + P + 129368064);       // 3538944
    u16*   Wph   = (u16*)(ws + P + 132907008);       // 1179648
    u16*   Wpl   = (u16*)(ws + P + 134086656);       // 1179648
    float* stats = (float*)(ws + P + 135266304);     // 98304 (12288 rows x {m, 1/l})
    // phase B (MoE) overlays:
    u16*   W1T   = (u16*)(ws + P);                   // 37748736
    u16*   W2T   = (u16*)(ws + P + 37748736);        // 37748736
    u16*   h2    = (u16*)(ws + P + 75497472);        // 6291456
    float* h2f   = (float*)(ws + P + 81788928);      // 12582912
    u16*   xg    = (u16*)(ws + P + 94371840);        // 14155776
    u16*   hid   = (u16*)(ws + P + 108527616);       // 56623104
    float* yg    = (float*)(ws + P + 75497472);      // 28311552, overlays h2/h2f/xg

    int*   counts   = (int*)(ws + o_rout + 0);
    int*   seg      = (int*)(ws + o_rout + 64);
    int*   cursor   = (int*)(ws + o_rout + 128);
    int*   topk_idx = (int*)(ws + o_rout + 1024);
    float* topk_w   = (float*)(ws + o_rout + 34816);
    int*   perm     = (int*)(ws + o_rout + 68608);
    float* gatew    = (float*)(ws + o_rout + 106496);
    int*   slot_of  = (int*)(ws + o_rout + 144384);

    const long EXPSTR = (long)DIMC * FFC;

    // ===== Phase A: attention (bf16x3 split precision) =====
    transpose_split_kernel<<<dim3(NQKVC/32, DIMC/32, 1), 256, 0, stream>>>(
        Wqkv, Wqh, Wql, NQKVC, DIMC, 0, 0);
    transpose_split_kernel<<<dim3(DIMC/32, DIMC/32, 1), 256, 0, stream>>>(
        Wproj, Wph, Wpl, DIMC, DIMC, 0, 0);
    ln_split_kernel<<<TOK, 256, 0, stream>>>(x, ln1g, ln1b, h1h, h1l);
    gemm3_kernel<0,2><<<dim3(NQKVC/128, TOK/128, 1), 256, 0, stream>>>(
        h1h, h1l, DIMC, 0, Wqh, Wql, DIMC, 0,
        qkvh, qkvl, NQKVC, 0, TOK, NQKVC, DIMC, 1.f, nullptr);
    // h1 dead now -> attf overlays it; zero for PV atomics
    (void)hipMemsetAsync(attf, 0, 12582912, stream);
    transpose_b2b_kernel<<<dim3(HDIM/32, SEQ/32, NBATCH*NHEAD), 256, 0, stream>>>(
        qkvh + 2 * DIMC, VTh, NQKVC, SEQ, (long)SEQ * NQKVC, NHEAD, (long)HDIM, (long)HDIM * SEQ);
    transpose_b2b_kernel<<<dim3(HDIM/32, SEQ/32, NBATCH*NHEAD), 256, 0, stream>>>(
        qkvl + 2 * DIMC, VTl, NQKVC, SEQ, (long)SEQ * NQKVC, NHEAD, (long)HDIM, (long)HDIM * SEQ);
    for (int b = 0; b < NBATCH; b++) {
        const u16* qbh = qkvh + (size_t)b * SEQ * NQKVC;
        const u16* qbl = qkvl + (size_t)b * SEQ * NQKVC;
        gemm3_kernel<0,1><<<dim3(SEQ/128, SEQ/128, NHEAD), 256, 0, stream>>>(
            qbh, qbl, NQKVC, (long)HDIM,
            qbh + DIMC, qbl + DIMC, NQKVC, (long)HDIM,
            Sc, nullptr, SEQ, (long)SEQ * SEQ,
            SEQ, SEQ, HDIM, 0.125f, nullptr);
        softmax_stats_kernel<<<NHEAD * SEQ, 256, 0, stream>>>(Sc, stats);
        pv_fused_kernel<<<dim3(4, SEQ/64, NHEAD), 256, 0, stream>>>(
            Sc, stats,
            VTh + (size_t)b * NHEAD * HDIM * SEQ, VTl + (size_t)b * NHEAD * HDIM * SEQ,
            attf, b);
    }
    split_hl_kernel<<<(TOK * DIMC) / 1024, 256, 0, stream>>>(attf, atth, attl);
    gemm3_kernel<3,1><<<dim3(DIMC/128, TOK/128, 1), 256, 0, stream>>>(
        atth, attl, DIMC, 0, Wph, Wpl, DIMC, 0,
        x1, nullptr, DIMC, 0, TOK, DIMC, DIMC, 1.f, x);

    // ===== Phase B: MoE (overlays phase-A pool) =====
    transpose_f2b_kernel<<<dim3(FFC/32, DIMC/32, NEXP), 256, 0, stream>>>(
        W1, W1T, FFC, DIMC, EXPSTR, EXPSTR);
    transpose_f2b_kernel<<<dim3(DIMC/32, FFC/32, NEXP), 256, 0, stream>>>(
        W2, W2T, DIMC, FFC, EXPSTR, EXPSTR);
    ln_bf_kernel<<<TOK, 256, 0, stream>>>(x1, ln2g, ln2b, h2, h2f);
    (void)hipMemsetAsync(ws + o_rout, 0, 262144, stream);
    router_kernel<<<TOK, 256, 0, stream>>>(h2f, Wrouter, topk_idx, topk_w, counts);
    offsets_kernel<<<1, 64, 0, stream>>>(counts, seg, cursor);
    build_perm_kernel<<<16, 256, 0, stream>>>(topk_idx, topk_w, cursor, perm, gatew, slot_of);
    gather_kernel<<<SLOTS, 192, 0, stream>>>(h2, perm, xg);
    // hid = gelu(xg @ W1[e])  bf16 out — BK64 + XCD swizzle
    gemm1_kernel<<<1728, 256, 0, stream>>>(xg, W1T, hid, seg);
    // yg = hid @ W2[e]  f32 out — BK64 + XCD swizzle
    gemm2_kernel<<<864, 256, 0, stream>>>(hid, W2T, yg, seg);
    combine_kernel<<<TOK, 192, 0, stream>>>(x1, yg, gatew, slot_of, out);

    (void)in_sizes; (void)n_in; (void)out_size;
}